// Round 2
// baseline (282.464 us; speedup 1.0000x reference)
//
#include <hip/hip_runtime.h>

// ---------------------------------------------------------------------------
// H_DYNA: fused 24-step recurrent memory-attention GRU on MI355X (gfx950).
// One prep kernel (bf16 MFMA fragment packing) + one fused main kernel.
// Each (b,n) row is independent -> wave handles 16 rows for its node across
// all 24 steps; state in registers; all matmuls via mfma_f32_16x16x32_bf16.
// Gates use hi/lo bf16 split (fp32-equivalent); attention path single bf16.
// ---------------------------------------------------------------------------

typedef short short8 __attribute__((ext_vector_type(8)));   // 8 x bf16 bits
typedef float f32x4 __attribute__((ext_vector_type(4)));

#define DEV static __device__ __forceinline__

DEV unsigned short f2bf(float f) {
  union { float f; unsigned u; } v; v.f = f;
  unsigned r = v.u + 0x7FFFu + ((v.u >> 16) & 1u);   // RNE
  return (unsigned short)(r >> 16);
}
DEV float bf2f(unsigned short b) {
  union { unsigned u; float f; } v; v.u = ((unsigned)b) << 16;
  return v.f;
}

// ---- ws layout (ushort units) ----
#define WG_OFF  36864   // mem frags: 72 frags * 512
#define WQ_OFF  61440   // gate-W frags: 48 * 512
#define LM_OFF  63488   // Wq frags: 4 * 512
#define GM_OFF  65536   // lmean frags: 4 * 512
#define WS_TOT  66560   // gmean frags: 2 * 512

// ---- LDS layout (bytes) ----
#define L_WG   73728          // mem frags occupy [0, 73728)
#define L_SCR  122880         // gate-W frags [73728, 122880)
#define SMEM_BYTES 139264     // + 4 waves * 4096 scratch

#define MFMA16(a, b, c) __builtin_amdgcn_mfma_f32_16x16x32_bf16((a), (b), (c), 0, 0, 0)

// ===========================================================================
// Prep: pack memory / weight matrices into MFMA B-fragment order (bf16).
// B-frag convention (16x16x32): col = lane&15, k = (lane>>4)*8 + j.
// ===========================================================================
__global__ __launch_bounds__(256, 1) void dyna_prep(
    const float* __restrict__ lmem, const float* __restrict__ gmem,
    const float* __restrict__ Wq, const float* __restrict__ Wz,
    const float* __restrict__ Wr, const float* __restrict__ Wc,
    unsigned short* __restrict__ ws)
{
  int i = blockIdx.x * 256 + threadIdx.x;
  if (i >= WS_TOT) return;

  if (i < WG_OFF) {                       // score-memory frags: [s 0..11][nt 0..5]
    int f = i >> 9, r = i & 511, lane = r >> 3, j = r & 7;
    int g = lane >> 4, u = lane & 15;
    int s = f / 6, nt = f % 6;
    int m = nt * 16 + u, p = g * 8 + j;   // k-dim = p (0..31)
    float v = (m < 64) ? lmem[(m * 12 + s) * 32 + p]
                       : gmem[((m - 64) * 12 + s) * 32 + p];
    ws[i] = f2bf(v);
  } else if (i < WQ_OFF) {                // gate W frags: fid=((gate*4+nt)*2+kc)*2+hl
    int t = i - WG_OFF;
    int f = t >> 9, r = t & 511, lane = r >> 3, j = r & 7;
    int g = lane >> 4, u = lane & 15;
    int hl = f & 1, kc = (f >> 1) & 1, nt = (f >> 2) & 3, gate = f >> 4;
    int k = kc * 32 + g * 8 + j, col = nt * 16 + u;
    const float* W = (gate == 0) ? Wz : (gate == 1) ? Wr : Wc;
    float w = W[(1 + k) * 64 + col];      // row 0 is the x-input row (handled in VALU)
    if (hl) { float hi = bf2f(f2bf(w)); ws[i] = f2bf(w - hi); }
    else ws[i] = f2bf(w);
  } else if (i < LM_OFF) {                // Wq frags: fid = nt*2+kc
    int t = i - WQ_OFF;
    int f = t >> 9, r = t & 511, lane = r >> 3, j = r & 7;
    int g = lane >> 4, u = lane & 15;
    int kc = f & 1, nt = f >> 1;
    int k = kc * 32 + g * 8 + j, col = nt * 16 + u;
    ws[i] = f2bf(Wq[k * 32 + col]);
  } else if (i < GM_OFF) {                // lmean frags: fid = kc*2+nt
    int t = i - LM_OFF;
    int f = t >> 9, r = t & 511, lane = r >> 3, j = r & 7;
    int g = lane >> 4, u = lane & 15;
    int kc = f >> 1, nt = f & 1;
    int k = kc * 32 + g * 8 + j, p = nt * 16 + u;   // k-dim = m (0..63)
    float s = 0.f;
    for (int ss = 0; ss < 12; ++ss) s += lmem[(k * 12 + ss) * 32 + p];
    ws[i] = f2bf(s * (1.0f / 12.0f));
  } else {                                // gmean frags: fid = nt
    int t = i - GM_OFF;
    int f = t >> 9, r = t & 511, lane = r >> 3, j = r & 7;
    int g = lane >> 4, u = lane & 15;
    int nt = f;
    int k = g * 8 + j, p = nt * 16 + u;
    float s = 0.f;
    for (int ss = 0; ss < 12; ++ss) s += gmem[(k * 12 + ss) * 32 + p];
    ws[i] = f2bf(s * (1.0f / 12.0f));
  }
}

// ===========================================================================
// Main fused kernel. Grid 256 blocks * 256 thr. Block = nodes {2g, 2g+1};
// wave w: node 2g+(w>>1), batch half (w&1), rows b = hb*16 + 4*(lane>>4)+reg.
// C-layout: col = lane&15 (=u), row = 4*(lane>>4)+reg (verified m89).
// Scratch round-trips are written in A-frag order (read = linear lane*16).
// ===========================================================================
__global__ __launch_bounds__(256, 1) void dyna_main(
    const float* __restrict__ src, const float* __restrict__ emb,
    const float* __restrict__ pool, const float* __restrict__ bq,
    const float* __restrict__ Wz, const float* __restrict__ bz,
    const float* __restrict__ Wr, const float* __restrict__ br,
    const float* __restrict__ Wc, const float* __restrict__ bc,
    const float* __restrict__ Wo, const float* __restrict__ bo,
    const unsigned short* __restrict__ ws, float* __restrict__ out)
{
  extern __shared__ char smem[];
  const int tid = threadIdx.x;
  const int lane = tid & 63, wid = tid >> 6;
  const int g = lane >> 4, u = lane & 15;
  const int n = blockIdx.x * 2 + (wid >> 1);
  const int hb = wid & 1;

  // ---- stage mem + gate-W frags to LDS (61440 ushorts = 7680 x 16B) ----
  {
    const short8* s8 = (const short8*)ws;
    short8* d8 = (short8*)smem;
    #pragma unroll 4
    for (int i = tid; i < 7680; i += 256) d8[i] = s8[i];
  }

  // ---- hoisted (time-invariant) B-frags in registers ----
  short8 wqf[2][2], lmf[2][2], gmf[2], nswf[2][4];
  #pragma unroll
  for (int kc = 0; kc < 2; ++kc)
    #pragma unroll
    for (int nt = 0; nt < 2; ++nt) {
      wqf[kc][nt] = *(const short8*)(ws + WQ_OFF + (nt * 2 + kc) * 512 + lane * 8);
      lmf[kc][nt] = *(const short8*)(ws + LM_OFF + (kc * 2 + nt) * 512 + lane * 8);
    }
  gmf[0] = *(const short8*)(ws + GM_OFF + lane * 8);
  gmf[1] = *(const short8*)(ws + GM_OFF + 512 + lane * 8);

  // nsw[n] = emb[n] @ pool, built directly as B-frags (K = f-dim 0..63)
  #pragma unroll
  for (int kc = 0; kc < 2; ++kc)
    #pragma unroll
    for (int nt = 0; nt < 4; ++nt) {
      short8 v;
      #pragma unroll
      for (int j = 0; j < 8; ++j) {
        int k = kc * 32 + g * 8 + j, col = nt * 16 + u;
        float s = 0.f;
        #pragma unroll
        for (int d = 0; d < 10; ++d)
          s += emb[n * 10 + d] * pool[(d * 64 + k) * 64 + col];
        v[j] = (short)f2bf(s);
      }
      nswf[kc][nt] = v;
    }

  // ---- per-lane constants (x-row weights, biases, Wo) ----
  float w0z[4], w0r[4], w0c[4], bzv[4], brv[4], bcv[4], wov[4], bqv[2];
  #pragma unroll
  for (int nt = 0; nt < 4; ++nt) {
    int col = nt * 16 + u;
    w0z[nt] = Wz[col]; w0r[nt] = Wr[col]; w0c[nt] = Wc[col];
    bzv[nt] = bz[col]; brv[nt] = br[col]; bcv[nt] = bc[col];
    wov[nt] = Wo[col];
  }
  bqv[0] = bq[u]; bqv[1] = bq[16 + u];
  const float bov = bo[0];

  char* scr = smem + L_SCR + wid * 4096;

  // ---- persistent per-row state ----
  short8 qh[12];                      // q-history A-frags (k = p-dim)
  {
    short8 qi;
    #pragma unroll
    for (int j = 0; j < 8; ++j) qi[j] = (short)f2bf(bq[g * 8 + j]);  // q(h=0) = bq
    #pragma unroll
    for (int s = 0; s < 12; ++s) qh[s] = qi;
  }
  f32x4 hreg[4];                      // h in C-layout [4 tiles][4 rows]
  #pragma unroll
  for (int nt = 0; nt < 4; ++nt) hreg[nt] = (f32x4){0.f, 0.f, 0.f, 0.f};
  float xreg[4] = {0.f, 0.f, 0.f, 0.f};

  __syncthreads();

  for (int t = 0; t < 24; ++t) {
    // ---- x input: encoder t<12 from source[:,t]; t==12 from source[:,11];
    //      t>12 autoregressive (y from previous step, already in xreg) ----
    if (t <= 12) {
      int tt = t < 12 ? t : 11;
      #pragma unroll
      for (int reg = 0; reg < 4; ++reg) {
        int b = hb * 16 + g * 4 + reg;
        xreg[reg] = src[(b * 12 + tt) * 512 + n];
      }
    }

    // ---- scores: [16 x 384] @ [384 x 96], K-chunk s pairs q-slot s with mem slot s ----
    f32x4 sacc[6];
    #pragma unroll
    for (int nt = 0; nt < 6; ++nt) sacc[nt] = (f32x4){0.f, 0.f, 0.f, 0.f};
    #pragma unroll
    for (int s = 0; s < 12; ++s) {
      #pragma unroll
      for (int nt = 0; nt < 6; ++nt) {
        short8 bf = *(const short8*)(smem + ((s * 6 + nt) << 10) + (lane << 4));
        sacc[nt] = MFMA16(qh[s], bf, sacc[nt]);
      }
    }

    // ---- softmax (local m 0..63 = tiles 0..3, global m 0..31 = tiles 4..5) ----
    #pragma unroll
    for (int reg = 0; reg < 4; ++reg) {
      float mx = fmaxf(fmaxf(sacc[0][reg], sacc[1][reg]),
                       fmaxf(sacc[2][reg], sacc[3][reg]));
      mx = fmaxf(mx, __shfl_xor(mx, 1)); mx = fmaxf(mx, __shfl_xor(mx, 2));
      mx = fmaxf(mx, __shfl_xor(mx, 4)); mx = fmaxf(mx, __shfl_xor(mx, 8));
      float e0 = __expf(sacc[0][reg] - mx), e1 = __expf(sacc[1][reg] - mx);
      float e2 = __expf(sacc[2][reg] - mx), e3 = __expf(sacc[3][reg] - mx);
      float sm = e0 + e1 + e2 + e3;
      sm += __shfl_xor(sm, 1); sm += __shfl_xor(sm, 2);
      sm += __shfl_xor(sm, 4); sm += __shfl_xor(sm, 8);
      float inv = 1.0f / sm;
      sacc[0][reg] = e0 * inv; sacc[1][reg] = e1 * inv;
      sacc[2][reg] = e2 * inv; sacc[3][reg] = e3 * inv;

      float mg = fmaxf(sacc[4][reg], sacc[5][reg]);
      mg = fmaxf(mg, __shfl_xor(mg, 1)); mg = fmaxf(mg, __shfl_xor(mg, 2));
      mg = fmaxf(mg, __shfl_xor(mg, 4)); mg = fmaxf(mg, __shfl_xor(mg, 8));
      float f0 = __expf(sacc[4][reg] - mg), f1 = __expf(sacc[5][reg] - mg);
      float sg = f0 + f1;
      sg += __shfl_xor(sg, 1); sg += __shfl_xor(sg, 2);
      sg += __shfl_xor(sg, 4); sg += __shfl_xor(sg, 8);
      float ig = 1.0f / sg;
      sacc[4][reg] = f0 * ig; sacc[5][reg] = f1 * ig;
    }

    __syncthreads();                             // prev-step scratch reads done
    // ---- a_l (chunks 0,1) + a_g (at +2048) scatter into A-frag order ----
    #pragma unroll
    for (int nt = 0; nt < 4; ++nt) {
      int m = nt * 16 + u, kp = m & 31;
      char* base = scr + ((m >> 5) << 10);
      #pragma unroll
      for (int reg = 0; reg < 4; ++reg)
        *(unsigned short*)(base + ((((kp >> 3) << 4) + g * 4 + reg) << 4) +
                           ((kp & 7) << 1)) = f2bf(sacc[nt][reg]);
    }
    #pragma unroll
    for (int nt = 0; nt < 2; ++nt) {
      int m = nt * 16 + u;
      #pragma unroll
      for (int reg = 0; reg < 4; ++reg)
        *(unsigned short*)(scr + 2048 + ((((m >> 3) << 4) + g * 4 + reg) << 4) +
                           ((m & 7) << 1)) = f2bf(sacc[4 + nt][reg]);
    }
    __syncthreads();
    short8 alf0 = *(const short8*)(scr + (lane << 4));
    short8 alf1 = *(const short8*)(scr + 1024 + (lane << 4));
    short8 agf  = *(const short8*)(scr + 2048 + (lane << 4));

    // ---- lc = a_l @ lmean, gc = a_g @ gmean ----
    f32x4 lacc[2], gacc[2];
    #pragma unroll
    for (int nt = 0; nt < 2; ++nt) {
      lacc[nt] = (f32x4){0.f, 0.f, 0.f, 0.f};
      gacc[nt] = (f32x4){0.f, 0.f, 0.f, 0.f};
      lacc[nt] = MFMA16(alf0, lmf[0][nt], lacc[nt]);
      lacc[nt] = MFMA16(alf1, lmf[1][nt], lacc[nt]);
      gacc[nt] = MFMA16(agf, gmf[nt], gacc[nt]);
    }

    __syncthreads();
    // ---- fused = [lc | gc] scatter (chunk0 = lc, chunk1 = gc) ----
    #pragma unroll
    for (int nt = 0; nt < 2; ++nt) {
      int kp = nt * 16 + u;
      int off = ((((kp >> 3) << 4) + g * 4) << 4) + ((kp & 7) << 1);
      #pragma unroll
      for (int reg = 0; reg < 4; ++reg) {
        *(unsigned short*)(scr + off + (reg << 4)) = f2bf(lacc[nt][reg]);
        *(unsigned short*)(scr + 1024 + off + (reg << 4)) = f2bf(gacc[nt][reg]);
      }
    }
    __syncthreads();
    short8 fuf0 = *(const short8*)(scr + (lane << 4));
    short8 fuf1 = *(const short8*)(scr + 1024 + (lane << 4));

    // ---- ctx = fused @ nsw[n] ----
    f32x4 cacc[4];
    #pragma unroll
    for (int nt = 0; nt < 4; ++nt) {
      cacc[nt] = (f32x4){0.f, 0.f, 0.f, 0.f};
      cacc[nt] = MFMA16(fuf0, nswf[0][nt], cacc[nt]);
      cacc[nt] = MFMA16(fuf1, nswf[1][nt], cacc[nt]);
    }

    __syncthreads();
    // ---- h -> A-frags, hi/lo split (hi chunks at 0,1024; lo at 2048,3072) ----
    #pragma unroll
    for (int nt = 0; nt < 4; ++nt) {
      int col = nt * 16 + u, kp = col & 31;
      char* base = scr + ((col >> 5) << 10);
      #pragma unroll
      for (int reg = 0; reg < 4; ++reg) {
        float hv = hreg[nt][reg];
        unsigned short hb16 = f2bf(hv);
        float lov = hv - bf2f(hb16);
        int off = ((((kp >> 3) << 4) + g * 4 + reg) << 4) + ((kp & 7) << 1);
        *(unsigned short*)(base + off) = hb16;
        *(unsigned short*)(base + 2048 + off) = f2bf(lov);
      }
    }
    __syncthreads();
    short8 hhi0 = *(const short8*)(scr + (lane << 4));
    short8 hhi1 = *(const short8*)(scr + 1024 + (lane << 4));
    short8 hlo0 = *(const short8*)(scr + 2048 + (lane << 4));
    short8 hlo1 = *(const short8*)(scr + 3072 + (lane << 4));

    // ---- z, r gates: split-precision MFMA (hh*Wh + hl*Wh + hh*Wl) ----
    f32x4 zacc[4], racc[4];
    #pragma unroll
    for (int nt = 0; nt < 4; ++nt) {
      zacc[nt] = (f32x4){0.f, 0.f, 0.f, 0.f};
      racc[nt] = (f32x4){0.f, 0.f, 0.f, 0.f};
    }
    #pragma unroll
    for (int kc = 0; kc < 2; ++kc) {
      short8 hh = kc ? hhi1 : hhi0;
      short8 hl = kc ? hlo1 : hlo0;
      #pragma unroll
      for (int nt = 0; nt < 4; ++nt) {
        short8 wzh = *(const short8*)(smem + L_WG + ((((nt * 2 + kc) * 2 + 0)) << 10) + (lane << 4));
        short8 wzl = *(const short8*)(smem + L_WG + ((((nt * 2 + kc) * 2 + 1)) << 10) + (lane << 4));
        zacc[nt] = MFMA16(hh, wzh, zacc[nt]);
        zacc[nt] = MFMA16(hl, wzh, zacc[nt]);
        zacc[nt] = MFMA16(hh, wzl, zacc[nt]);
        short8 wrh = *(const short8*)(smem + L_WG + (((((4 + nt) * 2 + kc) * 2 + 0)) << 10) + (lane << 4));
        short8 wrl = *(const short8*)(smem + L_WG + (((((4 + nt) * 2 + kc) * 2 + 1)) << 10) + (lane << 4));
        racc[nt] = MFMA16(hh, wrh, racc[nt]);
        racc[nt] = MFMA16(hl, wrh, racc[nt]);
        racc[nt] = MFMA16(hh, wrl, racc[nt]);
      }
    }
    #pragma unroll
    for (int nt = 0; nt < 4; ++nt)
      #pragma unroll
      for (int reg = 0; reg < 4; ++reg) {
        float zv = zacc[nt][reg] + xreg[reg] * w0z[nt] + bzv[nt];
        zacc[nt][reg] = 1.0f / (1.0f + __expf(-zv));
        float rv = racc[nt][reg] + xreg[reg] * w0r[nt] + brv[nt];
        racc[nt][reg] = 1.0f / (1.0f + __expf(-rv));
      }

    __syncthreads();
    // ---- rh = r * h  -> A-frags hi/lo ----
    #pragma unroll
    for (int nt = 0; nt < 4; ++nt) {
      int col = nt * 16 + u, kp = col & 31;
      char* base = scr + ((col >> 5) << 10);
      #pragma unroll
      for (int reg = 0; reg < 4; ++reg) {
        float rhv = racc[nt][reg] * hreg[nt][reg];
        unsigned short hb16 = f2bf(rhv);
        float lov = rhv - bf2f(hb16);
        int off = ((((kp >> 3) << 4) + g * 4 + reg) << 4) + ((kp & 7) << 1);
        *(unsigned short*)(base + off) = hb16;
        *(unsigned short*)(base + 2048 + off) = f2bf(lov);
      }
    }
    __syncthreads();
    short8 rhh0 = *(const short8*)(scr + (lane << 4));
    short8 rhh1 = *(const short8*)(scr + 1024 + (lane << 4));
    short8 rhl0 = *(const short8*)(scr + 2048 + (lane << 4));
    short8 rhl1 = *(const short8*)(scr + 3072 + (lane << 4));

    // ---- hc preact = ctx + rh @ Wc(hi/lo) + x*Wc0 + bc ; tanh ; h update ----
    f32x4 hacc[4];
    #pragma unroll
    for (int nt = 0; nt < 4; ++nt) hacc[nt] = cacc[nt];
    #pragma unroll
    for (int kc = 0; kc < 2; ++kc) {
      short8 hh = kc ? rhh1 : rhh0;
      short8 hl = kc ? rhl1 : rhl0;
      #pragma unroll
      for (int nt = 0; nt < 4; ++nt) {
        short8 wch = *(const short8*)(smem + L_WG + (((((8 + nt) * 2 + kc) * 2 + 0)) << 10) + (lane << 4));
        short8 wcl = *(const short8*)(smem + L_WG + (((((8 + nt) * 2 + kc) * 2 + 1)) << 10) + (lane << 4));
        hacc[nt] = MFMA16(hh, wch, hacc[nt]);
        hacc[nt] = MFMA16(hl, wch, hacc[nt]);
        hacc[nt] = MFMA16(hh, wcl, hacc[nt]);
      }
    }
    #pragma unroll
    for (int nt = 0; nt < 4; ++nt)
      #pragma unroll
      for (int reg = 0; reg < 4; ++reg) {
        float pv = hacc[nt][reg] + xreg[reg] * w0c[nt] + bcv[nt];
        float hc = 1.0f - 2.0f / (1.0f + __expf(2.0f * pv));   // tanh(pv)
        float zv = zacc[nt][reg];
        hreg[nt][reg] = (1.0f - zv) * hreg[nt][reg] + zv * hc;
      }

    __syncthreads();
    // ---- new h -> A-frags (hi only; q path tolerant) ----
    #pragma unroll
    for (int nt = 0; nt < 4; ++nt) {
      int col = nt * 16 + u, kp = col & 31;
      char* base = scr + ((col >> 5) << 10);
      #pragma unroll
      for (int reg = 0; reg < 4; ++reg)
        *(unsigned short*)(base + ((((kp >> 3) << 4) + g * 4 + reg) << 4) +
                           ((kp & 7) << 1)) = f2bf(hreg[nt][reg]);
    }
    __syncthreads();
    short8 nh0 = *(const short8*)(scr + (lane << 4));
    short8 nh1 = *(const short8*)(scr + 1024 + (lane << 4));

    // ---- qnew = h_new @ Wq + bq ----
    f32x4 qacc[2];
    #pragma unroll
    for (int nt = 0; nt < 2; ++nt) {
      qacc[nt] = (f32x4){0.f, 0.f, 0.f, 0.f};
      qacc[nt] = MFMA16(nh0, wqf[0][nt], qacc[nt]);
      qacc[nt] = MFMA16(nh1, wqf[1][nt], qacc[nt]);
    }
    __syncthreads();                       // nh reads done before overwrite
    #pragma unroll
    for (int nt = 0; nt < 2; ++nt) {
      int kp = nt * 16 + u;
      #pragma unroll
      for (int reg = 0; reg < 4; ++reg)
        *(unsigned short*)(scr + ((((kp >> 3) << 4) + g * 4 + reg) << 4) +
                           ((kp & 7) << 1)) = f2bf(qacc[nt][reg] + bqv[nt]);
    }
    __syncthreads();
    short8 qnf = *(const short8*)(scr + (lane << 4));
    #pragma unroll
    for (int s = 0; s < 11; ++s) qh[s] = qh[s + 1];   // ring shift (static idx)
    qh[11] = qnf;

    // ---- decoder head: y = h @ Wo + bo (feeds next x; store t>=12) ----
    if (t >= 12) {
      #pragma unroll
      for (int reg = 0; reg < 4; ++reg) {
        float yp = hreg[0][reg] * wov[0] + hreg[1][reg] * wov[1] +
                   hreg[2][reg] * wov[2] + hreg[3][reg] * wov[3];
        yp += __shfl_xor(yp, 1); yp += __shfl_xor(yp, 2);
        yp += __shfl_xor(yp, 4); yp += __shfl_xor(yp, 8);
        float yv = yp + bov;
        xreg[reg] = yv;
        if (u == 0) {
          int b = hb * 16 + g * 4 + reg;
          out[(b * 12 + (t - 12)) * 512 + n] = yv;
        }
      }
    }
  }
}

// ===========================================================================
extern "C" void kernel_launch(void* const* d_in, const int* in_sizes, int n_in,
                              void* d_out, int out_size, void* d_ws, size_t ws_size,
                              hipStream_t stream) {
  const float* src  = (const float*)d_in[0];
  const float* lmem = (const float*)d_in[1];
  const float* gmem = (const float*)d_in[2];
  const float* Wq   = (const float*)d_in[3];
  const float* bq   = (const float*)d_in[4];
  const float* emb  = (const float*)d_in[5];
  const float* pool = (const float*)d_in[6];
  const float* Wz   = (const float*)d_in[7];
  const float* bz   = (const float*)d_in[8];
  const float* Wr   = (const float*)d_in[9];
  const float* br   = (const float*)d_in[10];
  const float* Wc   = (const float*)d_in[11];
  const float* bc   = (const float*)d_in[12];
  const float* Wo   = (const float*)d_in[13];
  const float* bo   = (const float*)d_in[14];
  float* out = (float*)d_out;
  unsigned short* ws = (unsigned short*)d_ws;

  dyna_prep<<<260, 256, 0, stream>>>(lmem, gmem, Wq, Wz, Wr, Wc, ws);

  (void)hipFuncSetAttribute((const void*)dyna_main,
                            hipFuncAttributeMaxDynamicSharedMemorySize,
                            SMEM_BYTES);
  dyna_main<<<256, 256, SMEM_BYTES, stream>>>(src, emb, pool, bq, Wz, bz, Wr, br,
                                              Wc, bc, Wo, bo, ws, out);
}

// Round 3
// 274.549 us; speedup vs baseline: 1.0288x; 1.0288x over previous
//
#include <hip/hip_runtime.h>

// ---------------------------------------------------------------------------
// H_DYNA: fused 24-step recurrent memory-attention GRU on MI355X (gfx950).
// R3 change vs R2: removed ALL 12 in-loop __syncthreads (scratch is
// wave-private; same-wave DS ordering via compiler lgkmcnt suffices) so the
// 4 waves free-run and overlap DS/VALU/MFMA pipes; s_setprio around the
// score MFMA cluster (phase-diverse waves = the regime where T5 pays).
// ---------------------------------------------------------------------------

typedef short short8 __attribute__((ext_vector_type(8)));   // 8 x bf16 bits
typedef float f32x4 __attribute__((ext_vector_type(4)));

#define DEV static __device__ __forceinline__

DEV unsigned short f2bf(float f) {
  union { float f; unsigned u; } v; v.f = f;
  unsigned r = v.u + 0x7FFFu + ((v.u >> 16) & 1u);   // RNE
  return (unsigned short)(r >> 16);
}
DEV float bf2f(unsigned short b) {
  union { unsigned u; float f; } v; v.u = ((unsigned)b) << 16;
  return v.f;
}

// ---- ws layout (ushort units) ----
#define WG_OFF  36864   // mem frags: 72 frags * 512
#define WQ_OFF  61440   // gate-W frags: 48 * 512
#define LM_OFF  63488   // Wq frags: 4 * 512
#define GM_OFF  65536   // lmean frags: 4 * 512
#define WS_TOT  66560   // gmean frags: 2 * 512

// ---- LDS layout (bytes) ----
#define L_WG   73728          // mem frags occupy [0, 73728)
#define L_SCR  122880         // gate-W frags [73728, 122880)
#define SMEM_BYTES 139264     // + 4 waves * 4096 scratch

#define MFMA16(a, b, c) __builtin_amdgcn_mfma_f32_16x16x32_bf16((a), (b), (c), 0, 0, 0)

// ===========================================================================
// Prep: pack memory / weight matrices into MFMA B-fragment order (bf16).
// B-frag convention (16x16x32): col = lane&15, k = (lane>>4)*8 + j.
// ===========================================================================
__global__ __launch_bounds__(256, 1) void dyna_prep(
    const float* __restrict__ lmem, const float* __restrict__ gmem,
    const float* __restrict__ Wq, const float* __restrict__ Wz,
    const float* __restrict__ Wr, const float* __restrict__ Wc,
    unsigned short* __restrict__ ws)
{
  int i = blockIdx.x * 256 + threadIdx.x;
  if (i >= WS_TOT) return;

  if (i < WG_OFF) {                       // score-memory frags: [s 0..11][nt 0..5]
    int f = i >> 9, r = i & 511, lane = r >> 3, j = r & 7;
    int g = lane >> 4, u = lane & 15;
    int s = f / 6, nt = f % 6;
    int m = nt * 16 + u, p = g * 8 + j;   // k-dim = p (0..31)
    float v = (m < 64) ? lmem[(m * 12 + s) * 32 + p]
                       : gmem[((m - 64) * 12 + s) * 32 + p];
    ws[i] = f2bf(v);
  } else if (i < WQ_OFF) {                // gate W frags: fid=((gate*4+nt)*2+kc)*2+hl
    int t = i - WG_OFF;
    int f = t >> 9, r = t & 511, lane = r >> 3, j = r & 7;
    int g = lane >> 4, u = lane & 15;
    int hl = f & 1, kc = (f >> 1) & 1, nt = (f >> 2) & 3, gate = f >> 4;
    int k = kc * 32 + g * 8 + j, col = nt * 16 + u;
    const float* W = (gate == 0) ? Wz : (gate == 1) ? Wr : Wc;
    float w = W[(1 + k) * 64 + col];      // row 0 is the x-input row (handled in VALU)
    if (hl) { float hi = bf2f(f2bf(w)); ws[i] = f2bf(w - hi); }
    else ws[i] = f2bf(w);
  } else if (i < LM_OFF) {                // Wq frags: fid = nt*2+kc
    int t = i - WQ_OFF;
    int f = t >> 9, r = t & 511, lane = r >> 3, j = r & 7;
    int g = lane >> 4, u = lane & 15;
    int kc = f & 1, nt = f >> 1;
    int k = kc * 32 + g * 8 + j, col = nt * 16 + u;
    ws[i] = f2bf(Wq[k * 32 + col]);
  } else if (i < GM_OFF) {                // lmean frags: fid = kc*2+nt
    int t = i - LM_OFF;
    int f = t >> 9, r = t & 511, lane = r >> 3, j = r & 7;
    int g = lane >> 4, u = lane & 15;
    int kc = f >> 1, nt = f & 1;
    int k = kc * 32 + g * 8 + j, p = nt * 16 + u;   // k-dim = m (0..63)
    float s = 0.f;
    for (int ss = 0; ss < 12; ++ss) s += lmem[(k * 12 + ss) * 32 + p];
    ws[i] = f2bf(s * (1.0f / 12.0f));
  } else {                                // gmean frags: fid = nt
    int t = i - GM_OFF;
    int f = t >> 9, r = t & 511, lane = r >> 3, j = r & 7;
    int g = lane >> 4, u = lane & 15;
    int nt = f;
    int k = g * 8 + j, p = nt * 16 + u;
    float s = 0.f;
    for (int ss = 0; ss < 12; ++ss) s += gmem[(k * 12 + ss) * 32 + p];
    ws[i] = f2bf(s * (1.0f / 12.0f));
  }
}

// ===========================================================================
// Main fused kernel. Grid 256 blocks * 256 thr. Block = nodes {2g, 2g+1};
// wave w: node 2g+(w>>1), batch half (w&1), rows b = hb*16 + 4*(lane>>4)+reg.
// C-layout: col = lane&15 (=u), row = 4*(lane>>4)+reg (verified m89).
// Scratch round-trips are written in A-frag order (read = linear lane*16).
// Scratch is WAVE-PRIVATE (scr = base + wid*4096) -> no block barriers in the
// step loop; same-wave ds_write->ds_read ordering is enforced by lgkmcnt.
// ===========================================================================
__global__ __launch_bounds__(256, 1) void dyna_main(
    const float* __restrict__ src, const float* __restrict__ emb,
    const float* __restrict__ pool, const float* __restrict__ bq,
    const float* __restrict__ Wz, const float* __restrict__ bz,
    const float* __restrict__ Wr, const float* __restrict__ br,
    const float* __restrict__ Wc, const float* __restrict__ bc,
    const float* __restrict__ Wo, const float* __restrict__ bo,
    const unsigned short* __restrict__ ws, float* __restrict__ out)
{
  extern __shared__ char smem[];
  const int tid = threadIdx.x;
  const int lane = tid & 63, wid = tid >> 6;
  const int g = lane >> 4, u = lane & 15;
  const int n = blockIdx.x * 2 + (wid >> 1);
  const int hb = wid & 1;

  // ---- stage mem + gate-W frags to LDS (61440 ushorts = 7680 x 16B) ----
  {
    const short8* s8 = (const short8*)ws;
    short8* d8 = (short8*)smem;
    #pragma unroll 4
    for (int i = tid; i < 7680; i += 256) d8[i] = s8[i];
  }

  // ---- hoisted (time-invariant) B-frags in registers ----
  short8 wqf[2][2], lmf[2][2], gmf[2], nswf[2][4];
  #pragma unroll
  for (int kc = 0; kc < 2; ++kc)
    #pragma unroll
    for (int nt = 0; nt < 2; ++nt) {
      wqf[kc][nt] = *(const short8*)(ws + WQ_OFF + (nt * 2 + kc) * 512 + lane * 8);
      lmf[kc][nt] = *(const short8*)(ws + LM_OFF + (kc * 2 + nt) * 512 + lane * 8);
    }
  gmf[0] = *(const short8*)(ws + GM_OFF + lane * 8);
  gmf[1] = *(const short8*)(ws + GM_OFF + 512 + lane * 8);

  // nsw[n] = emb[n] @ pool, built directly as B-frags (K = f-dim 0..63)
  #pragma unroll
  for (int kc = 0; kc < 2; ++kc)
    #pragma unroll
    for (int nt = 0; nt < 4; ++nt) {
      short8 v;
      #pragma unroll
      for (int j = 0; j < 8; ++j) {
        int k = kc * 32 + g * 8 + j, col = nt * 16 + u;
        float s = 0.f;
        #pragma unroll
        for (int d = 0; d < 10; ++d)
          s += emb[n * 10 + d] * pool[(d * 64 + k) * 64 + col];
        v[j] = (short)f2bf(s);
      }
      nswf[kc][nt] = v;
    }

  // ---- per-lane constants (x-row weights, biases, Wo) ----
  float w0z[4], w0r[4], w0c[4], bzv[4], brv[4], bcv[4], wov[4], bqv[2];
  #pragma unroll
  for (int nt = 0; nt < 4; ++nt) {
    int col = nt * 16 + u;
    w0z[nt] = Wz[col]; w0r[nt] = Wr[col]; w0c[nt] = Wc[col];
    bzv[nt] = bz[col]; brv[nt] = br[col]; bcv[nt] = bc[col];
    wov[nt] = Wo[col];
  }
  bqv[0] = bq[u]; bqv[1] = bq[16 + u];
  const float bov = bo[0];

  char* scr = smem + L_SCR + wid * 4096;

  // ---- persistent per-row state ----
  short8 qh[12];                      // q-history A-frags (k = p-dim)
  {
    short8 qi;
    #pragma unroll
    for (int j = 0; j < 8; ++j) qi[j] = (short)f2bf(bq[g * 8 + j]);  // q(h=0) = bq
    #pragma unroll
    for (int s = 0; s < 12; ++s) qh[s] = qi;
  }
  f32x4 hreg[4];                      // h in C-layout [4 tiles][4 rows]
  #pragma unroll
  for (int nt = 0; nt < 4; ++nt) hreg[nt] = (f32x4){0.f, 0.f, 0.f, 0.f};
  float xreg[4] = {0.f, 0.f, 0.f, 0.f};

  __syncthreads();    // staged frags visible to all waves; the ONLY barrier

  for (int t = 0; t < 24; ++t) {
    // ---- x input: encoder t<12 from source[:,t]; t==12 from source[:,11];
    //      t>12 autoregressive (y from previous step, already in xreg) ----
    if (t <= 12) {
      int tt = t < 12 ? t : 11;
      #pragma unroll
      for (int reg = 0; reg < 4; ++reg) {
        int b = hb * 16 + g * 4 + reg;
        xreg[reg] = src[(b * 12 + tt) * 512 + n];
      }
    }

    // ---- scores: [16 x 384] @ [384 x 96], K-chunk s pairs q-slot s with mem slot s ----
    f32x4 sacc[6];
    #pragma unroll
    for (int nt = 0; nt < 6; ++nt) sacc[nt] = (f32x4){0.f, 0.f, 0.f, 0.f};
    __builtin_amdgcn_s_setprio(1);
    #pragma unroll
    for (int s = 0; s < 12; ++s) {
      #pragma unroll
      for (int nt = 0; nt < 6; ++nt) {
        short8 bf = *(const short8*)(smem + ((s * 6 + nt) << 10) + (lane << 4));
        sacc[nt] = MFMA16(qh[s], bf, sacc[nt]);
      }
    }
    __builtin_amdgcn_s_setprio(0);

    // ---- softmax (local m 0..63 = tiles 0..3, global m 0..31 = tiles 4..5) ----
    #pragma unroll
    for (int reg = 0; reg < 4; ++reg) {
      float mx = fmaxf(fmaxf(sacc[0][reg], sacc[1][reg]),
                       fmaxf(sacc[2][reg], sacc[3][reg]));
      mx = fmaxf(mx, __shfl_xor(mx, 1)); mx = fmaxf(mx, __shfl_xor(mx, 2));
      mx = fmaxf(mx, __shfl_xor(mx, 4)); mx = fmaxf(mx, __shfl_xor(mx, 8));
      float e0 = __expf(sacc[0][reg] - mx), e1 = __expf(sacc[1][reg] - mx);
      float e2 = __expf(sacc[2][reg] - mx), e3 = __expf(sacc[3][reg] - mx);
      float sm = e0 + e1 + e2 + e3;
      sm += __shfl_xor(sm, 1); sm += __shfl_xor(sm, 2);
      sm += __shfl_xor(sm, 4); sm += __shfl_xor(sm, 8);
      float inv = 1.0f / sm;
      sacc[0][reg] = e0 * inv; sacc[1][reg] = e1 * inv;
      sacc[2][reg] = e2 * inv; sacc[3][reg] = e3 * inv;

      float mg = fmaxf(sacc[4][reg], sacc[5][reg]);
      mg = fmaxf(mg, __shfl_xor(mg, 1)); mg = fmaxf(mg, __shfl_xor(mg, 2));
      mg = fmaxf(mg, __shfl_xor(mg, 4)); mg = fmaxf(mg, __shfl_xor(mg, 8));
      float f0 = __expf(sacc[4][reg] - mg), f1 = __expf(sacc[5][reg] - mg);
      float sg = f0 + f1;
      sg += __shfl_xor(sg, 1); sg += __shfl_xor(sg, 2);
      sg += __shfl_xor(sg, 4); sg += __shfl_xor(sg, 8);
      float ig = 1.0f / sg;
      sacc[4][reg] = f0 * ig; sacc[5][reg] = f1 * ig;
    }

    // ---- a_l (chunks 0,1) + a_g (at +2048) scatter into A-frag order ----
    // (wave-private scratch; same-wave lgkmcnt ordering, no barrier)
    #pragma unroll
    for (int nt = 0; nt < 4; ++nt) {
      int m = nt * 16 + u, kp = m & 31;
      char* base = scr + ((m >> 5) << 10);
      #pragma unroll
      for (int reg = 0; reg < 4; ++reg)
        *(unsigned short*)(base + ((((kp >> 3) << 4) + g * 4 + reg) << 4) +
                           ((kp & 7) << 1)) = f2bf(sacc[nt][reg]);
    }
    #pragma unroll
    for (int nt = 0; nt < 2; ++nt) {
      int m = nt * 16 + u;
      #pragma unroll
      for (int reg = 0; reg < 4; ++reg)
        *(unsigned short*)(scr + 2048 + ((((m >> 3) << 4) + g * 4 + reg) << 4) +
                           ((m & 7) << 1)) = f2bf(sacc[4 + nt][reg]);
    }
    short8 alf0 = *(const short8*)(scr + (lane << 4));
    short8 alf1 = *(const short8*)(scr + 1024 + (lane << 4));
    short8 agf  = *(const short8*)(scr + 2048 + (lane << 4));

    // ---- lc = a_l @ lmean, gc = a_g @ gmean ----
    f32x4 lacc[2], gacc[2];
    #pragma unroll
    for (int nt = 0; nt < 2; ++nt) {
      lacc[nt] = (f32x4){0.f, 0.f, 0.f, 0.f};
      gacc[nt] = (f32x4){0.f, 0.f, 0.f, 0.f};
      lacc[nt] = MFMA16(alf0, lmf[0][nt], lacc[nt]);
      lacc[nt] = MFMA16(alf1, lmf[1][nt], lacc[nt]);
      gacc[nt] = MFMA16(agf, gmf[nt], gacc[nt]);
    }

    // ---- fused = [lc | gc] scatter (chunk0 = lc, chunk1 = gc) ----
    #pragma unroll
    for (int nt = 0; nt < 2; ++nt) {
      int kp = nt * 16 + u;
      int off = ((((kp >> 3) << 4) + g * 4) << 4) + ((kp & 7) << 1);
      #pragma unroll
      for (int reg = 0; reg < 4; ++reg) {
        *(unsigned short*)(scr + off + (reg << 4)) = f2bf(lacc[nt][reg]);
        *(unsigned short*)(scr + 1024 + off + (reg << 4)) = f2bf(gacc[nt][reg]);
      }
    }
    short8 fuf0 = *(const short8*)(scr + (lane << 4));
    short8 fuf1 = *(const short8*)(scr + 1024 + (lane << 4));

    // ---- ctx = fused @ nsw[n] ----
    f32x4 cacc[4];
    #pragma unroll
    for (int nt = 0; nt < 4; ++nt) {
      cacc[nt] = (f32x4){0.f, 0.f, 0.f, 0.f};
      cacc[nt] = MFMA16(fuf0, nswf[0][nt], cacc[nt]);
      cacc[nt] = MFMA16(fuf1, nswf[1][nt], cacc[nt]);
    }

    // ---- h -> A-frags, hi/lo split (hi chunks at 0,1024; lo at 2048,3072) ----
    #pragma unroll
    for (int nt = 0; nt < 4; ++nt) {
      int col = nt * 16 + u, kp = col & 31;
      char* base = scr + ((col >> 5) << 10);
      #pragma unroll
      for (int reg = 0; reg < 4; ++reg) {
        float hv = hreg[nt][reg];
        unsigned short hb16 = f2bf(hv);
        float lov = hv - bf2f(hb16);
        int off = ((((kp >> 3) << 4) + g * 4 + reg) << 4) + ((kp & 7) << 1);
        *(unsigned short*)(base + off) = hb16;
        *(unsigned short*)(base + 2048 + off) = f2bf(lov);
      }
    }
    short8 hhi0 = *(const short8*)(scr + (lane << 4));
    short8 hhi1 = *(const short8*)(scr + 1024 + (lane << 4));
    short8 hlo0 = *(const short8*)(scr + 2048 + (lane << 4));
    short8 hlo1 = *(const short8*)(scr + 3072 + (lane << 4));

    // ---- z, r gates: split-precision MFMA (hh*Wh + hl*Wh + hh*Wl) ----
    f32x4 zacc[4], racc[4];
    #pragma unroll
    for (int nt = 0; nt < 4; ++nt) {
      zacc[nt] = (f32x4){0.f, 0.f, 0.f, 0.f};
      racc[nt] = (f32x4){0.f, 0.f, 0.f, 0.f};
    }
    #pragma unroll
    for (int kc = 0; kc < 2; ++kc) {
      short8 hh = kc ? hhi1 : hhi0;
      short8 hl = kc ? hlo1 : hlo0;
      #pragma unroll
      for (int nt = 0; nt < 4; ++nt) {
        short8 wzh = *(const short8*)(smem + L_WG + ((((nt * 2 + kc) * 2 + 0)) << 10) + (lane << 4));
        short8 wzl = *(const short8*)(smem + L_WG + ((((nt * 2 + kc) * 2 + 1)) << 10) + (lane << 4));
        zacc[nt] = MFMA16(hh, wzh, zacc[nt]);
        zacc[nt] = MFMA16(hl, wzh, zacc[nt]);
        zacc[nt] = MFMA16(hh, wzl, zacc[nt]);
        short8 wrh = *(const short8*)(smem + L_WG + (((((4 + nt) * 2 + kc) * 2 + 0)) << 10) + (lane << 4));
        short8 wrl = *(const short8*)(smem + L_WG + (((((4 + nt) * 2 + kc) * 2 + 1)) << 10) + (lane << 4));
        racc[nt] = MFMA16(hh, wrh, racc[nt]);
        racc[nt] = MFMA16(hl, wrh, racc[nt]);
        racc[nt] = MFMA16(hh, wrl, racc[nt]);
      }
    }
    #pragma unroll
    for (int nt = 0; nt < 4; ++nt)
      #pragma unroll
      for (int reg = 0; reg < 4; ++reg) {
        float zv = zacc[nt][reg] + xreg[reg] * w0z[nt] + bzv[nt];
        zacc[nt][reg] = 1.0f / (1.0f + __expf(-zv));
        float rv = racc[nt][reg] + xreg[reg] * w0r[nt] + brv[nt];
        racc[nt][reg] = 1.0f / (1.0f + __expf(-rv));
      }

    // ---- rh = r * h  -> A-frags hi/lo ----
    #pragma unroll
    for (int nt = 0; nt < 4; ++nt) {
      int col = nt * 16 + u, kp = col & 31;
      char* base = scr + ((col >> 5) << 10);
      #pragma unroll
      for (int reg = 0; reg < 4; ++reg) {
        float rhv = racc[nt][reg] * hreg[nt][reg];
        unsigned short hb16 = f2bf(rhv);
        float lov = rhv - bf2f(hb16);
        int off = ((((kp >> 3) << 4) + g * 4 + reg) << 4) + ((kp & 7) << 1);
        *(unsigned short*)(base + off) = hb16;
        *(unsigned short*)(base + 2048 + off) = f2bf(lov);
      }
    }
    short8 rhh0 = *(const short8*)(scr + (lane << 4));
    short8 rhh1 = *(const short8*)(scr + 1024 + (lane << 4));
    short8 rhl0 = *(const short8*)(scr + 2048 + (lane << 4));
    short8 rhl1 = *(const short8*)(scr + 3072 + (lane << 4));

    // ---- hc preact = ctx + rh @ Wc(hi/lo) + x*Wc0 + bc ; tanh ; h update ----
    f32x4 hacc[4];
    #pragma unroll
    for (int nt = 0; nt < 4; ++nt) hacc[nt] = cacc[nt];
    #pragma unroll
    for (int kc = 0; kc < 2; ++kc) {
      short8 hh = kc ? rhh1 : rhh0;
      short8 hl = kc ? rhl1 : rhl0;
      #pragma unroll
      for (int nt = 0; nt < 4; ++nt) {
        short8 wch = *(const short8*)(smem + L_WG + (((((8 + nt) * 2 + kc) * 2 + 0)) << 10) + (lane << 4));
        short8 wcl = *(const short8*)(smem + L_WG + (((((8 + nt) * 2 + kc) * 2 + 1)) << 10) + (lane << 4));
        hacc[nt] = MFMA16(hh, wch, hacc[nt]);
        hacc[nt] = MFMA16(hl, wch, hacc[nt]);
        hacc[nt] = MFMA16(hh, wcl, hacc[nt]);
      }
    }
    #pragma unroll
    for (int nt = 0; nt < 4; ++nt)
      #pragma unroll
      for (int reg = 0; reg < 4; ++reg) {
        float pv = hacc[nt][reg] + xreg[reg] * w0c[nt] + bcv[nt];
        float hc = 1.0f - 2.0f / (1.0f + __expf(2.0f * pv));   // tanh(pv)
        float zv = zacc[nt][reg];
        hreg[nt][reg] = (1.0f - zv) * hreg[nt][reg] + zv * hc;
      }

    // ---- new h -> A-frags (hi only; q path tolerant) ----
    #pragma unroll
    for (int nt = 0; nt < 4; ++nt) {
      int col = nt * 16 + u, kp = col & 31;
      char* base = scr + ((col >> 5) << 10);
      #pragma unroll
      for (int reg = 0; reg < 4; ++reg)
        *(unsigned short*)(base + ((((kp >> 3) << 4) + g * 4 + reg) << 4) +
                           ((kp & 7) << 1)) = f2bf(hreg[nt][reg]);
    }
    short8 nh0 = *(const short8*)(scr + (lane << 4));
    short8 nh1 = *(const short8*)(scr + 1024 + (lane << 4));

    // ---- qnew = h_new @ Wq + bq ----
    f32x4 qacc[2];
    #pragma unroll
    for (int nt = 0; nt < 2; ++nt) {
      qacc[nt] = (f32x4){0.f, 0.f, 0.f, 0.f};
      qacc[nt] = MFMA16(nh0, wqf[0][nt], qacc[nt]);
      qacc[nt] = MFMA16(nh1, wqf[1][nt], qacc[nt]);
    }
    #pragma unroll
    for (int nt = 0; nt < 2; ++nt) {
      int kp = nt * 16 + u;
      #pragma unroll
      for (int reg = 0; reg < 4; ++reg)
        *(unsigned short*)(scr + ((((kp >> 3) << 4) + g * 4 + reg) << 4) +
                           ((kp & 7) << 1)) = f2bf(qacc[nt][reg] + bqv[nt]);
    }
    short8 qnf = *(const short8*)(scr + (lane << 4));
    #pragma unroll
    for (int s = 0; s < 11; ++s) qh[s] = qh[s + 1];   // ring shift (static idx)
    qh[11] = qnf;

    // ---- decoder head: y = h @ Wo + bo (feeds next x; store t>=12) ----
    if (t >= 12) {
      #pragma unroll
      for (int reg = 0; reg < 4; ++reg) {
        float yp = hreg[0][reg] * wov[0] + hreg[1][reg] * wov[1] +
                   hreg[2][reg] * wov[2] + hreg[3][reg] * wov[3];
        yp += __shfl_xor(yp, 1); yp += __shfl_xor(yp, 2);
        yp += __shfl_xor(yp, 4); yp += __shfl_xor(yp, 8);
        float yv = yp + bov;
        xreg[reg] = yv;
        if (u == 0) {
          int b = hb * 16 + g * 4 + reg;
          out[(b * 12 + (t - 12)) * 512 + n] = yv;
        }
      }
    }
  }
}

// ===========================================================================
extern "C" void kernel_launch(void* const* d_in, const int* in_sizes, int n_in,
                              void* d_out, int out_size, void* d_ws, size_t ws_size,
                              hipStream_t stream) {
  const float* src  = (const float*)d_in[0];
  const float* lmem = (const float*)d_in[1];
  const float* gmem = (const float*)d_in[2];
  const float* Wq   = (const float*)d_in[3];
  const float* bq   = (const float*)d_in[4];
  const float* emb  = (const float*)d_in[5];
  const float* pool = (const float*)d_in[6];
  const float* Wz   = (const float*)d_in[7];
  const float* bz   = (const float*)d_in[8];
  const float* Wr   = (const float*)d_in[9];
  const float* br   = (const float*)d_in[10];
  const float* Wc   = (const float*)d_in[11];
  const float* bc   = (const float*)d_in[12];
  const float* Wo   = (const float*)d_in[13];
  const float* bo   = (const float*)d_in[14];
  float* out = (float*)d_out;
  unsigned short* ws = (unsigned short*)d_ws;

  dyna_prep<<<260, 256, 0, stream>>>(lmem, gmem, Wq, Wz, Wr, Wc, ws);

  (void)hipFuncSetAttribute((const void*)dyna_main,
                            hipFuncAttributeMaxDynamicSharedMemorySize,
                            SMEM_BYTES);
  dyna_main<<<256, 256, SMEM_BYTES, stream>>>(src, emb, pool, bq, Wz, bz, Wr, br,
                                              Wc, bc, Wo, bo, ws, out);
}

// Round 5
// 235.071 us; speedup vs baseline: 1.2016x; 1.1679x over previous
//
#include <hip/hip_runtime.h>

// ---------------------------------------------------------------------------
// H_DYNA: fused 24-step recurrent memory-attention GRU on MI355X (gfx950).
// R4 changes vs R3 (per-wave serial-chain attack; occupancy is NOT the lever):
//  - gate W-hi fragments live in REGISTERS (96 VGPR), W-lo + lmean/gmean in LDS
//  - all scatter bf16 conversions via v_cvt_pk_bf16_f32 (1 inst / 2 values)
//  - softmax: no max-subtract (scores bounded), unnormalized-e scatter,
//    1/sum folded in after the attention MFMA; raw v_rcp for sigm/tanh/inv
//  - disjoint per-phase scratch regions so h-RT hides under the score loop
// ---------------------------------------------------------------------------

typedef short short8 __attribute__((ext_vector_type(8)));   // 8 x bf16 bits
typedef float f32x4 __attribute__((ext_vector_type(4)));

#define DEV static __device__ __forceinline__

DEV unsigned short f2bf(float f) {
  union { float f; unsigned u; } v; v.f = f;
  unsigned r = v.u + 0x7FFFu + ((v.u >> 16) & 1u);   // RNE
  return (unsigned short)(r >> 16);
}
DEV float bf2f(unsigned short b) {
  union { unsigned u; float f; } v; v.u = ((unsigned)b) << 16;
  return v.f;
}
DEV unsigned cvtpk(float a, float b) {                // packed RNE f32->bf16 x2
  unsigned r;
  asm("v_cvt_pk_bf16_f32 %0, %1, %2" : "=v"(r) : "v"(a), "v"(b));
  return r;
}
DEV float rcpf(float x) { return __builtin_amdgcn_rcpf(x); }

// ---- ws layout (ushort units) ----
#define WG_OFF  36864   // mem frags: 72 frags * 512
#define WQ_OFF  61440   // gate-W frags: 48 * 512 (hi/lo interleaved)
#define LM_OFF  63488   // Wq frags: 4 * 512
#define GM_OFF  65536   // lmean frags: 4 * 512
#define WS_TOT  66560   // gmean frags: 2 * 512

// ---- LDS layout (bytes) ----
#define L_WLO   73728         // mem frags [0, 73728); W-lo frags 24 KB here
#define L_LM    98304         // lmean 4 KB + gmean 2 KB
#define L_SCR   104448        // per-wave scratch
#define SCR_STRIDE 13312
#define SMEM_BYTES 157696     // 104448 + 4*13312

// per-wave scratch regions (disjoint per phase; NH/QQ reuse AL/AG safely)
#define R_AL 0
#define R_AG 2048
#define R_FU 3072
#define R_HH 5120
#define R_HL 7168
#define R_RH 9216
#define R_RL 11264
#define R_NH 0
#define R_QQ 2048

#define MFMA16(a, b, c) __builtin_amdgcn_mfma_f32_16x16x32_bf16((a), (b), (c), 0, 0, 0)

// A-frag scatter address: element (row = 4g+reg via +reg*16, k = col)
DEV int scat_off(int col, int g) {
  int kp = col & 31;
  return ((col >> 5) << 10) + ((kp >> 3) << 8) + (g << 6) + ((kp & 7) << 1);
}
DEV void scat4(char* p, f32x4 v) {        // 4 C-regs -> bf16 A-layout
  unsigned p0 = cvtpk(v[0], v[1]), p1 = cvtpk(v[2], v[3]);
  *(unsigned short*)(p)      = (unsigned short)p0;
  *(unsigned short*)(p + 16) = (unsigned short)(p0 >> 16);
  *(unsigned short*)(p + 32) = (unsigned short)p1;
  *(unsigned short*)(p + 48) = (unsigned short)(p1 >> 16);
}
DEV void scat4_hilo(char* ph, char* pl, f32x4 v) {   // hi/lo split scatter
  unsigned p0 = cvtpk(v[0], v[1]), p1 = cvtpk(v[2], v[3]);
  float h0 = __uint_as_float(p0 << 16), h1 = __uint_as_float(p0 & 0xFFFF0000u);
  float h2 = __uint_as_float(p1 << 16), h3 = __uint_as_float(p1 & 0xFFFF0000u);
  unsigned q0 = cvtpk(v[0] - h0, v[1] - h1), q1 = cvtpk(v[2] - h2, v[3] - h3);
  *(unsigned short*)(ph)      = (unsigned short)p0;
  *(unsigned short*)(ph + 16) = (unsigned short)(p0 >> 16);
  *(unsigned short*)(ph + 32) = (unsigned short)p1;
  *(unsigned short*)(ph + 48) = (unsigned short)(p1 >> 16);
  *(unsigned short*)(pl)      = (unsigned short)q0;
  *(unsigned short*)(pl + 16) = (unsigned short)(q0 >> 16);
  *(unsigned short*)(pl + 32) = (unsigned short)q1;
  *(unsigned short*)(pl + 48) = (unsigned short)(q1 >> 16);
}

// ===========================================================================
// Prep: pack memory / weight matrices into MFMA B-fragment order (bf16).
// ===========================================================================
__global__ __launch_bounds__(256, 1) void dyna_prep(
    const float* __restrict__ lmem, const float* __restrict__ gmem,
    const float* __restrict__ Wq, const float* __restrict__ Wz,
    const float* __restrict__ Wr, const float* __restrict__ Wc,
    unsigned short* __restrict__ ws)
{
  int i = blockIdx.x * 256 + threadIdx.x;
  if (i >= WS_TOT) return;

  if (i < WG_OFF) {                       // score-memory frags: [s 0..11][nt 0..5]
    int f = i >> 9, r = i & 511, lane = r >> 3, j = r & 7;
    int g = lane >> 4, u = lane & 15;
    int s = f / 6, nt = f % 6;
    int m = nt * 16 + u, p = g * 8 + j;
    float v = (m < 64) ? lmem[(m * 12 + s) * 32 + p]
                       : gmem[((m - 64) * 12 + s) * 32 + p];
    ws[i] = f2bf(v);
  } else if (i < WQ_OFF) {                // gate W frags: fid=((gate*4+nt)*2+kc)*2+hl
    int t = i - WG_OFF;
    int f = t >> 9, r = t & 511, lane = r >> 3, j = r & 7;
    int g = lane >> 4, u = lane & 15;
    int hl = f & 1, kc = (f >> 1) & 1, nt = (f >> 2) & 3, gate = f >> 4;
    int k = kc * 32 + g * 8 + j, col = nt * 16 + u;
    const float* W = (gate == 0) ? Wz : (gate == 1) ? Wr : Wc;
    float w = W[(1 + k) * 64 + col];
    if (hl) { float hi = bf2f(f2bf(w)); ws[i] = f2bf(w - hi); }
    else ws[i] = f2bf(w);
  } else if (i < LM_OFF) {                // Wq frags: fid = nt*2+kc
    int t = i - WQ_OFF;
    int f = t >> 9, r = t & 511, lane = r >> 3, j = r & 7;
    int g = lane >> 4, u = lane & 15;
    int kc = f & 1, nt = f >> 1;
    int k = kc * 32 + g * 8 + j, col = nt * 16 + u;
    ws[i] = f2bf(Wq[k * 32 + col]);
  } else if (i < GM_OFF) {                // lmean frags: fid = kc*2+nt
    int t = i - LM_OFF;
    int f = t >> 9, r = t & 511, lane = r >> 3, j = r & 7;
    int g = lane >> 4, u = lane & 15;
    int kc = f >> 1, nt = f & 1;
    int k = kc * 32 + g * 8 + j, p = nt * 16 + u;
    float s = 0.f;
    for (int ss = 0; ss < 12; ++ss) s += lmem[(k * 12 + ss) * 32 + p];
    ws[i] = f2bf(s * (1.0f / 12.0f));
  } else {                                // gmean frags: fid = nt
    int t = i - GM_OFF;
    int f = t >> 9, r = t & 511, lane = r >> 3, j = r & 7;
    int g = lane >> 4, u = lane & 15;
    int nt = f;
    int k = g * 8 + j, p = nt * 16 + u;
    float s = 0.f;
    for (int ss = 0; ss < 12; ++ss) s += gmem[(k * 12 + ss) * 32 + p];
    ws[i] = f2bf(s * (1.0f / 12.0f));
  }
}

// ===========================================================================
// Main fused kernel. 256 blocks * 256 thr. Block = nodes {2B, 2B+1};
// wave w: node 2B+(w>>1), batch half (w&1), rows = hb*16 + 4g+reg.
// ===========================================================================
__global__ __launch_bounds__(256, 1) void dyna_main(
    const float* __restrict__ src, const float* __restrict__ emb,
    const float* __restrict__ pool, const float* __restrict__ bq,
    const float* __restrict__ Wz, const float* __restrict__ bz,
    const float* __restrict__ Wr, const float* __restrict__ br,
    const float* __restrict__ Wc, const float* __restrict__ bc,
    const float* __restrict__ Wo, const float* __restrict__ bo,
    const unsigned short* __restrict__ ws, float* __restrict__ out)
{
  extern __shared__ char smem[];
  const int tid = threadIdx.x;
  const int lane = tid & 63, wid = tid >> 6;
  const int g = lane >> 4, u = lane & 15;
  const int n = blockIdx.x * 2 + (wid >> 1);
  const int hb = wid & 1;

  // ---- stage mem frags + W-lo frags + lm/gm frags to LDS (6528 x 16B) ----
  {
    const short8* s8 = (const short8*)ws;
    short8* d8 = (short8*)smem;
    for (int i = tid; i < 6528; i += 256) {
      int s;
      if (i < 4608) s = i;                                   // mem frags
      else if (i < 6144) {                                   // W-lo (hl=1)
        int r = i - 4608;
        s = 4608 + ((r >> 6) << 7) + 64 + (r & 63);
      } else s = 7936 + (i - 6144);                          // lm + gm
      d8[i] = s8[s];
    }
  }

  // ---- register-resident fragments ----
  short8 whf[3][2][4];   // gate W hi [gate][kc][nt] - 96 VGPR
  #pragma unroll
  for (int gate = 0; gate < 3; ++gate)
    #pragma unroll
    for (int kc = 0; kc < 2; ++kc)
      #pragma unroll
      for (int nt = 0; nt < 4; ++nt) {
        int f = ((gate * 4 + nt) * 2 + kc) * 2;
        whf[gate][kc][nt] = *(const short8*)(ws + WG_OFF + f * 512 + lane * 8);
      }
  short8 wqf[2][2];
  #pragma unroll
  for (int kc = 0; kc < 2; ++kc)
    #pragma unroll
    for (int nt = 0; nt < 2; ++nt)
      wqf[kc][nt] = *(const short8*)(ws + WQ_OFF + (nt * 2 + kc) * 512 + lane * 8);

  // nsw[n] = emb[n] @ pool, built directly as B-frags (K = f-dim 0..63)
  short8 nswf[2][4];
  #pragma unroll
  for (int kc = 0; kc < 2; ++kc)
    #pragma unroll
    for (int nt = 0; nt < 4; ++nt) {
      short8 v;
      #pragma unroll
      for (int j = 0; j < 8; ++j) {
        int k = kc * 32 + g * 8 + j, col = nt * 16 + u;
        float s = 0.f;
        #pragma unroll
        for (int d = 0; d < 10; ++d)
          s += emb[n * 10 + d] * pool[(d * 64 + k) * 64 + col];
        v[j] = (short)f2bf(s);
      }
      nswf[kc][nt] = v;
    }

  // ---- per-lane constants ----
  float w0z[4], w0r[4], w0c[4], bzv[4], brv[4], bcv[4], wov[4], bqv[2];
  #pragma unroll
  for (int nt = 0; nt < 4; ++nt) {
    int col = nt * 16 + u;
    w0z[nt] = Wz[col]; w0r[nt] = Wr[col]; w0c[nt] = Wc[col];
    bzv[nt] = bz[col]; brv[nt] = br[col]; bcv[nt] = bc[col];
    wov[nt] = Wo[col];
  }
  bqv[0] = bq[u]; bqv[1] = bq[16 + u];
  const float bov = bo[0];

  char* SCR = smem + L_SCR + wid * SCR_STRIDE;

  // ---- persistent per-row state ----
  short8 qh[12];
  {
    short8 qi;
    #pragma unroll
    for (int j = 0; j < 8; ++j) qi[j] = (short)f2bf(bq[g * 8 + j]);
    #pragma unroll
    for (int s = 0; s < 12; ++s) qh[s] = qi;
  }
  f32x4 hreg[4];
  #pragma unroll
  for (int nt = 0; nt < 4; ++nt) hreg[nt] = (f32x4){0.f, 0.f, 0.f, 0.f};
  float xreg[4] = {0.f, 0.f, 0.f, 0.f};

  __syncthreads();    // staged frags visible; the only barrier

  for (int t = 0; t < 24; ++t) {
    // ---- x input ----
    if (t <= 12) {
      int tt = t < 12 ? t : 11;
      #pragma unroll
      for (int reg = 0; reg < 4; ++reg) {
        int b = hb * 16 + g * 4 + reg;
        xreg[reg] = src[(b * 12 + tt) * 512 + n];
      }
    }

    // ---- h_prev -> HH/HL hi/lo scatter (independent of scores; its
    //      round-trip latency hides under the 72-read score loop) ----
    #pragma unroll
    for (int nt = 0; nt < 4; ++nt) {
      int so = scat_off(nt * 16 + u, g);
      scat4_hilo(SCR + R_HH + so, SCR + R_HL + so, hreg[nt]);
    }

    // ---- scores: [16 x 384] @ [384 x 96] ----
    f32x4 sacc[6];
    #pragma unroll
    for (int nt = 0; nt < 6; ++nt) sacc[nt] = (f32x4){0.f, 0.f, 0.f, 0.f};
    __builtin_amdgcn_s_setprio(1);
    #pragma unroll
    for (int s = 0; s < 12; ++s) {
      #pragma unroll
      for (int nt = 0; nt < 6; ++nt) {
        short8 bf = *(const short8*)(smem + ((s * 6 + nt) << 10) + (lane << 4));
        sacc[nt] = MFMA16(qh[s], bf, sacc[nt]);
      }
    }
    __builtin_amdgcn_s_setprio(0);

    // ---- h-frag reads; z/r gate MFMA (W-hi from regs, W-lo from LDS) ----
    short8 hhi0 = *(const short8*)(SCR + R_HH + (lane << 4));
    short8 hhi1 = *(const short8*)(SCR + R_HH + 1024 + (lane << 4));
    short8 hlo0 = *(const short8*)(SCR + R_HL + (lane << 4));
    short8 hlo1 = *(const short8*)(SCR + R_HL + 1024 + (lane << 4));
    f32x4 zacc[4], racc[4];
    #pragma unroll
    for (int nt = 0; nt < 4; ++nt) {
      zacc[nt] = (f32x4){0.f, 0.f, 0.f, 0.f};
      racc[nt] = (f32x4){0.f, 0.f, 0.f, 0.f};
    }
    #pragma unroll
    for (int kc = 0; kc < 2; ++kc) {
      short8 hh = kc ? hhi1 : hhi0;
      short8 hl = kc ? hlo1 : hlo0;
      #pragma unroll
      for (int nt = 0; nt < 4; ++nt) {
        short8 wzl = *(const short8*)(smem + L_WLO + (((0 * 4 + nt) * 2 + kc) << 10) + (lane << 4));
        short8 wrl = *(const short8*)(smem + L_WLO + (((1 * 4 + nt) * 2 + kc) << 10) + (lane << 4));
        zacc[nt] = MFMA16(hh, whf[0][kc][nt], zacc[nt]);
        zacc[nt] = MFMA16(hl, whf[0][kc][nt], zacc[nt]);
        zacc[nt] = MFMA16(hh, wzl, zacc[nt]);
        racc[nt] = MFMA16(hh, whf[1][kc][nt], racc[nt]);
        racc[nt] = MFMA16(hl, whf[1][kc][nt], racc[nt]);
        racc[nt] = MFMA16(hh, wrl, racc[nt]);
      }
    }

    // ---- softmax-lite: e = exp(score) (bounded, no max-sub); sums ----
    #pragma unroll
    for (int nt = 0; nt < 6; ++nt)
      #pragma unroll
      for (int reg = 0; reg < 4; ++reg)
        sacc[nt][reg] = __expf(sacc[nt][reg]);
    float invl[4], invg[4];
    #pragma unroll
    for (int reg = 0; reg < 4; ++reg) {
      float sl = (sacc[0][reg] + sacc[1][reg]) + (sacc[2][reg] + sacc[3][reg]);
      sl += __shfl_xor(sl, 1); sl += __shfl_xor(sl, 2);
      sl += __shfl_xor(sl, 4); sl += __shfl_xor(sl, 8);
      invl[reg] = rcpf(sl);
      float sg = sacc[4][reg] + sacc[5][reg];
      sg += __shfl_xor(sg, 1); sg += __shfl_xor(sg, 2);
      sg += __shfl_xor(sg, 4); sg += __shfl_xor(sg, 8);
      invg[reg] = rcpf(sg);
    }

    // ---- unnormalized e scatter -> AL / AG ----
    #pragma unroll
    for (int nt = 0; nt < 4; ++nt)
      scat4(SCR + R_AL + scat_off(nt * 16 + u, g), sacc[nt]);
    #pragma unroll
    for (int nt = 0; nt < 2; ++nt)
      scat4(SCR + R_AG + scat_off(nt * 16 + u, g), sacc[4 + nt]);

    // ---- sigmoid gates ----
    #pragma unroll
    for (int nt = 0; nt < 4; ++nt)
      #pragma unroll
      for (int reg = 0; reg < 4; ++reg) {
        float zv = zacc[nt][reg] + xreg[reg] * w0z[nt] + bzv[nt];
        zacc[nt][reg] = rcpf(1.0f + __expf(-zv));
        float rv = racc[nt][reg] + xreg[reg] * w0r[nt] + brv[nt];
        racc[nt][reg] = rcpf(1.0f + __expf(-rv));
      }

    // ---- rh = r*h -> RH/RL hi/lo scatter (hides under attention MFMAs) ----
    #pragma unroll
    for (int nt = 0; nt < 4; ++nt) {
      int so = scat_off(nt * 16 + u, g);
      f32x4 rh;
      #pragma unroll
      for (int reg = 0; reg < 4; ++reg) rh[reg] = racc[nt][reg] * hreg[nt][reg];
      scat4_hilo(SCR + R_RH + so, SCR + R_RL + so, rh);
    }

    // ---- attention context: lc = e_l @ lmean, gc = e_g @ gmean ----
    short8 alf0 = *(const short8*)(SCR + R_AL + (lane << 4));
    short8 alf1 = *(const short8*)(SCR + R_AL + 1024 + (lane << 4));
    short8 agf  = *(const short8*)(SCR + R_AG + (lane << 4));
    f32x4 lacc[2], gacc[2];
    #pragma unroll
    for (int nt = 0; nt < 2; ++nt) {
      lacc[nt] = (f32x4){0.f, 0.f, 0.f, 0.f};
      gacc[nt] = (f32x4){0.f, 0.f, 0.f, 0.f};
      short8 lm0 = *(const short8*)(smem + L_LM + ((0 * 2 + nt) << 10) + (lane << 4));
      short8 lm1 = *(const short8*)(smem + L_LM + ((1 * 2 + nt) << 10) + (lane << 4));
      short8 gm  = *(const short8*)(smem + L_LM + 4096 + (nt << 10) + (lane << 4));
      lacc[nt] = MFMA16(alf0, lm0, lacc[nt]);
      lacc[nt] = MFMA16(alf1, lm1, lacc[nt]);
      gacc[nt] = MFMA16(agf, gm, gacc[nt]);
    }

    // ---- rh reads + Wc MFMA -> hacc ----
    short8 rhh0 = *(const short8*)(SCR + R_RH + (lane << 4));
    short8 rhh1 = *(const short8*)(SCR + R_RH + 1024 + (lane << 4));
    short8 rhl0 = *(const short8*)(SCR + R_RL + (lane << 4));
    short8 rhl1 = *(const short8*)(SCR + R_RL + 1024 + (lane << 4));
    f32x4 hacc[4];
    #pragma unroll
    for (int nt = 0; nt < 4; ++nt) hacc[nt] = (f32x4){0.f, 0.f, 0.f, 0.f};
    #pragma unroll
    for (int kc = 0; kc < 2; ++kc) {
      short8 hh = kc ? rhh1 : rhh0;
      short8 hl = kc ? rhl1 : rhl0;
      #pragma unroll
      for (int nt = 0; nt < 4; ++nt) {
        short8 wcl = *(const short8*)(smem + L_WLO + (((2 * 4 + nt) * 2 + kc) << 10) + (lane << 4));
        hacc[nt] = MFMA16(hh, whf[2][kc][nt], hacc[nt]);
        hacc[nt] = MFMA16(hl, whf[2][kc][nt], hacc[nt]);
        hacc[nt] = MFMA16(hh, wcl, hacc[nt]);
      }
    }

    // ---- fused = [lc*invl | gc*invg] scatter -> FU ----
    #pragma unroll
    for (int nt = 0; nt < 2; ++nt) {
      f32x4 lv, gv;
      #pragma unroll
      for (int reg = 0; reg < 4; ++reg) {
        lv[reg] = lacc[nt][reg] * invl[reg];
        gv[reg] = gacc[nt][reg] * invg[reg];
      }
      scat4(SCR + R_FU + scat_off(nt * 16 + u, g), lv);
      scat4(SCR + R_FU + scat_off(32 + nt * 16 + u, g), gv);
    }
    short8 fuf0 = *(const short8*)(SCR + R_FU + (lane << 4));
    short8 fuf1 = *(const short8*)(SCR + R_FU + 1024 + (lane << 4));

    // ---- ctx = fused @ nsw[n] ----
    f32x4 cacc[4];
    #pragma unroll
    for (int nt = 0; nt < 4; ++nt) {
      cacc[nt] = (f32x4){0.f, 0.f, 0.f, 0.f};
      cacc[nt] = MFMA16(fuf0, nswf[0][nt], cacc[nt]);
      cacc[nt] = MFMA16(fuf1, nswf[1][nt], cacc[nt]);
    }

    // ---- combine: tanh + GRU update ----
    #pragma unroll
    for (int nt = 0; nt < 4; ++nt)
      #pragma unroll
      for (int reg = 0; reg < 4; ++reg) {
        float pv = hacc[nt][reg] + cacc[nt][reg] + xreg[reg] * w0c[nt] + bcv[nt];
        float tdenom = rcpf(1.0f + __expf(2.0f * pv));
        float hc = 1.0f - 2.0f * tdenom;               // tanh(pv)
        float zv = zacc[nt][reg];
        hreg[nt][reg] = (1.0f - zv) * hreg[nt][reg] + zv * hc;
      }

    // ---- new h -> NH (reuses AL region; AL reads are done) ----
    #pragma unroll
    for (int nt = 0; nt < 4; ++nt)
      scat4(SCR + R_NH + scat_off(nt * 16 + u, g), hreg[nt]);
    short8 nh0 = *(const short8*)(SCR + R_NH + (lane << 4));
    short8 nh1 = *(const short8*)(SCR + R_NH + 1024 + (lane << 4));

    // ---- qnew = h_new @ Wq + bq ----
    f32x4 qacc[2];
    #pragma unroll
    for (int nt = 0; nt < 2; ++nt) {
      qacc[nt] = (f32x4){0.f, 0.f, 0.f, 0.f};
      qacc[nt] = MFMA16(nh0, wqf[0][nt], qacc[nt]);
      qacc[nt] = MFMA16(nh1, wqf[1][nt], qacc[nt]);
      #pragma unroll
      for (int reg = 0; reg < 4; ++reg) qacc[nt][reg] += bqv[nt];
    }
    #pragma unroll
    for (int nt = 0; nt < 2; ++nt)
      scat4(SCR + R_QQ + scat_off(nt * 16 + u, g), qacc[nt]);
    short8 qnf = *(const short8*)(SCR + R_QQ + (lane << 4));
    #pragma unroll
    for (int s = 0; s < 11; ++s) qh[s] = qh[s + 1];
    qh[11] = qnf;

    // ---- decoder head ----
    if (t >= 12) {
      #pragma unroll
      for (int reg = 0; reg < 4; ++reg) {
        float yp = hreg[0][reg] * wov[0] + hreg[1][reg] * wov[1] +
                   hreg[2][reg] * wov[2] + hreg[3][reg] * wov[3];
        yp += __shfl_xor(yp, 1); yp += __shfl_xor(yp, 2);
        yp += __shfl_xor(yp, 4); yp += __shfl_xor(yp, 8);
        float yv = yp + bov;
        xreg[reg] = yv;
        if (u == 0) {
          int b = hb * 16 + g * 4 + reg;
          out[(b * 12 + (t - 12)) * 512 + n] = yv;
        }
      }
    }
  }
}

// ===========================================================================
extern "C" void kernel_launch(void* const* d_in, const int* in_sizes, int n_in,
                              void* d_out, int out_size, void* d_ws, size_t ws_size,
                              hipStream_t stream) {
  const float* src  = (const float*)d_in[0];
  const float* lmem = (const float*)d_in[1];
  const float* gmem = (const float*)d_in[2];
  const float* Wq   = (const float*)d_in[3];
  const float* bq   = (const float*)d_in[4];
  const float* emb  = (const float*)d_in[5];
  const float* pool = (const float*)d_in[6];
  const float* Wz   = (const float*)d_in[7];
  const float* bz   = (const float*)d_in[8];
  const float* Wr   = (const float*)d_in[9];
  const float* br   = (const float*)d_in[10];
  const float* Wc   = (const float*)d_in[11];
  const float* bc   = (const float*)d_in[12];
  const float* Wo   = (const float*)d_in[13];
  const float* bo   = (const float*)d_in[14];
  float* out = (float*)d_out;
  unsigned short* ws = (unsigned short*)d_ws;

  dyna_prep<<<260, 256, 0, stream>>>(lmem, gmem, Wq, Wz, Wr, Wc, ws);

  (void)hipFuncSetAttribute((const void*)dyna_main,
                            hipFuncAttributeMaxDynamicSharedMemorySize,
                            SMEM_BYTES);
  dyna_main<<<256, 256, SMEM_BYTES, stream>>>(src, emb, pool, bq, Wz, bz, Wr, br,
                                              Wc, bc, Wo, bo, ws, out);
}

// Round 6
// 211.856 us; speedup vs baseline: 1.3333x; 1.1096x over previous
//
#include <hip/hip_runtime.h>

// ---------------------------------------------------------------------------
// H_DYNA: fused 24-step recurrent memory-attention GRU on MI355X (gfx950).
// R6 changes vs R5 (exploit 512-VGPR budget at the forced 1 wave/SIMD):
//  - 72 score-memory B-frags live in REGISTERS (288 VGPR, one-time global
//    load) -> score loop is pure-reg MFMA, 72 DS reads/step removed
//  - gate W hi+lo, Wq, nsw frags all in LDS (register relief)
//  - exp/e-scatter moved BEFORE gate MFMAs (sacc dies before zacc/racc born)
//  - single h hi/lo scatter at h-update serves q-path AND next-step gates
//  - h_prev frag reads issued at step start (hide under score MFMAs)
// ---------------------------------------------------------------------------

typedef short short8 __attribute__((ext_vector_type(8)));   // 8 x bf16 bits
typedef float f32x4 __attribute__((ext_vector_type(4)));

#define DEV static __device__ __forceinline__

DEV unsigned short f2bf(float f) {
  union { float f; unsigned u; } v; v.f = f;
  unsigned r = v.u + 0x7FFFu + ((v.u >> 16) & 1u);   // RNE
  return (unsigned short)(r >> 16);
}
DEV float bf2f(unsigned short b) {
  union { unsigned u; float f; } v; v.u = ((unsigned)b) << 16;
  return v.f;
}
DEV unsigned cvtpk(float a, float b) {                // packed RNE f32->bf16 x2
  unsigned r;
  asm("v_cvt_pk_bf16_f32 %0, %1, %2" : "=v"(r) : "v"(a), "v"(b));
  return r;
}
DEV float rcpf(float x) { return __builtin_amdgcn_rcpf(x); }

// ---- ws layout (ushort units) ----
#define WG_OFF  36864   // mem frags: 72 frags * 512 before this
#define WQ_OFF  61440   // gate-W frags: 48 * 512 (hi/lo interleaved)
#define LM_OFF  63488   // Wq frags: 4 * 512
#define GM_OFF  65536   // lmean frags: 4 * 512
#define WS_TOT  66560   // gmean frags: 2 * 512

// ---- LDS layout (bytes) ----
#define L_W     0             // 48 gate-W frags (fid order), 49152 B
#define L_WQ    49152         // 4 Wq frags
#define L_LM    53248         // lmean 4 + gmean 2 frags
#define L_SCR   59392         // per-wave scratch
#define SCR_STRIDE 21504
#define SMEM_BYTES 145408     // 59392 + 4*21504

// per-wave scratch regions
#define R_AL 0
#define R_AG 2048
#define R_FU 3072
#define R_HH 5120
#define R_HL 7168
#define R_RH 9216
#define R_RL 11264
#define R_NSW 13312           // 8 KB: nsw B-frags (per-wave copy)
#define R_QQ 0                // reuse AL after its reads

#define MFMA16(a, b, c) __builtin_amdgcn_mfma_f32_16x16x32_bf16((a), (b), (c), 0, 0, 0)

// A-frag scatter address for element (row = 4g+reg via +reg*16, k = col)
DEV int scat_off(int col, int g) {
  int kp = col & 31;
  return ((col >> 5) << 10) + ((kp >> 3) << 8) + (g << 6) + ((kp & 7) << 1);
}
DEV void scat4(char* p, f32x4 v) {        // 4 C-regs -> bf16 A-layout
  unsigned p0 = cvtpk(v[0], v[1]), p1 = cvtpk(v[2], v[3]);
  *(unsigned short*)(p)      = (unsigned short)p0;
  *(unsigned short*)(p + 16) = (unsigned short)(p0 >> 16);
  *(unsigned short*)(p + 32) = (unsigned short)p1;
  *(unsigned short*)(p + 48) = (unsigned short)(p1 >> 16);
}
DEV void scat4_hilo(char* ph, char* pl, f32x4 v) {   // hi/lo split scatter
  unsigned p0 = cvtpk(v[0], v[1]), p1 = cvtpk(v[2], v[3]);
  float h0 = __uint_as_float(p0 << 16), h1 = __uint_as_float(p0 & 0xFFFF0000u);
  float h2 = __uint_as_float(p1 << 16), h3 = __uint_as_float(p1 & 0xFFFF0000u);
  unsigned q0 = cvtpk(v[0] - h0, v[1] - h1), q1 = cvtpk(v[2] - h2, v[3] - h3);
  *(unsigned short*)(ph)      = (unsigned short)p0;
  *(unsigned short*)(ph + 16) = (unsigned short)(p0 >> 16);
  *(unsigned short*)(ph + 32) = (unsigned short)p1;
  *(unsigned short*)(ph + 48) = (unsigned short)(p1 >> 16);
  *(unsigned short*)(pl)      = (unsigned short)q0;
  *(unsigned short*)(pl + 16) = (unsigned short)(q0 >> 16);
  *(unsigned short*)(pl + 32) = (unsigned short)q1;
  *(unsigned short*)(pl + 48) = (unsigned short)(q1 >> 16);
}

// ===========================================================================
// Prep: pack memory / weight matrices into MFMA B-fragment order (bf16).
// (unchanged from R5)
// ===========================================================================
__global__ __launch_bounds__(256, 1) void dyna_prep(
    const float* __restrict__ lmem, const float* __restrict__ gmem,
    const float* __restrict__ Wq, const float* __restrict__ Wz,
    const float* __restrict__ Wr, const float* __restrict__ Wc,
    unsigned short* __restrict__ ws)
{
  int i = blockIdx.x * 256 + threadIdx.x;
  if (i >= WS_TOT) return;

  if (i < WG_OFF) {                       // score-memory frags: [s 0..11][nt 0..5]
    int f = i >> 9, r = i & 511, lane = r >> 3, j = r & 7;
    int g = lane >> 4, u = lane & 15;
    int s = f / 6, nt = f % 6;
    int m = nt * 16 + u, p = g * 8 + j;
    float v = (m < 64) ? lmem[(m * 12 + s) * 32 + p]
                       : gmem[((m - 64) * 12 + s) * 32 + p];
    ws[i] = f2bf(v);
  } else if (i < WQ_OFF) {                // gate W frags: fid=((gate*4+nt)*2+kc)*2+hl
    int t = i - WG_OFF;
    int f = t >> 9, r = t & 511, lane = r >> 3, j = r & 7;
    int g = lane >> 4, u = lane & 15;
    int hl = f & 1, kc = (f >> 1) & 1, nt = (f >> 2) & 3, gate = f >> 4;
    int k = kc * 32 + g * 8 + j, col = nt * 16 + u;
    const float* W = (gate == 0) ? Wz : (gate == 1) ? Wr : Wc;
    float w = W[(1 + k) * 64 + col];
    if (hl) { float hi = bf2f(f2bf(w)); ws[i] = f2bf(w - hi); }
    else ws[i] = f2bf(w);
  } else if (i < LM_OFF) {                // Wq frags: fid = nt*2+kc
    int t = i - WQ_OFF;
    int f = t >> 9, r = t & 511, lane = r >> 3, j = r & 7;
    int g = lane >> 4, u = lane & 15;
    int kc = f & 1, nt = f >> 1;
    int k = kc * 32 + g * 8 + j, col = nt * 16 + u;
    ws[i] = f2bf(Wq[k * 32 + col]);
  } else if (i < GM_OFF) {                // lmean frags: fid = kc*2+nt
    int t = i - LM_OFF;
    int f = t >> 9, r = t & 511, lane = r >> 3, j = r & 7;
    int g = lane >> 4, u = lane & 15;
    int kc = f >> 1, nt = f & 1;
    int k = kc * 32 + g * 8 + j, p = nt * 16 + u;
    float s = 0.f;
    for (int ss = 0; ss < 12; ++ss) s += lmem[(k * 12 + ss) * 32 + p];
    ws[i] = f2bf(s * (1.0f / 12.0f));
  } else {                                // gmean frags: fid = nt
    int t = i - GM_OFF;
    int f = t >> 9, r = t & 511, lane = r >> 3, j = r & 7;
    int g = lane >> 4, u = lane & 15;
    int nt = f;
    int k = g * 8 + j, p = nt * 16 + u;
    float s = 0.f;
    for (int ss = 0; ss < 12; ++ss) s += gmem[(k * 12 + ss) * 32 + p];
    ws[i] = f2bf(s * (1.0f / 12.0f));
  }
}

// ===========================================================================
// Main fused kernel. 256 blocks * 256 thr. Block = nodes {2B, 2B+1};
// wave w: node 2B+(w>>1), batch half (w&1), rows = hb*16 + 4g+reg.
// ===========================================================================
__global__ __launch_bounds__(256, 1) void dyna_main(
    const float* __restrict__ src, const float* __restrict__ emb,
    const float* __restrict__ pool, const float* __restrict__ bq,
    const float* __restrict__ Wz, const float* __restrict__ bz,
    const float* __restrict__ Wr, const float* __restrict__ br,
    const float* __restrict__ Wc, const float* __restrict__ bc,
    const float* __restrict__ Wo, const float* __restrict__ bo,
    const unsigned short* __restrict__ ws, float* __restrict__ out)
{
  extern __shared__ char smem[];
  const int tid = threadIdx.x;
  const int lane = tid & 63, wid = tid >> 6;
  const int g = lane >> 4, u = lane & 15;
  const int n = blockIdx.x * 2 + (wid >> 1);
  const int hb = wid & 1;

  // ---- stage W (48) + Wq (4) + lm/gm (6) frags: ws is contiguous here ----
  {
    const short8* s8 = (const short8*)ws;
    short8* d8 = (short8*)smem;
    for (int i = tid; i < 3712; i += 256) d8[i] = s8[4608 + i];  // 4608 = WG_OFF/8
  }

  // ---- 72 score-memory B-frags -> registers (one-time global load) ----
  short8 marr[72];
  #pragma unroll
  for (int f = 0; f < 72; ++f)
    marr[f] = *(const short8*)(ws + (f << 9) + lane * 8);

  char* SCR = smem + L_SCR + wid * SCR_STRIDE;

  // ---- nsw[n] = emb[n] @ pool, built as B-frags, stored in per-wave LDS ----
  #pragma unroll
  for (int kc = 0; kc < 2; ++kc)
    #pragma unroll
    for (int nt = 0; nt < 4; ++nt) {
      short8 v;
      #pragma unroll
      for (int j = 0; j < 8; ++j) {
        int k = kc * 32 + g * 8 + j, col = nt * 16 + u;
        float s = 0.f;
        #pragma unroll
        for (int d = 0; d < 10; ++d)
          s += emb[n * 10 + d] * pool[(d * 64 + k) * 64 + col];
        v[j] = (short)f2bf(s);
      }
      *(short8*)(SCR + R_NSW + ((kc * 4 + nt) << 10) + (lane << 4)) = v;
    }

  // ---- per-lane constants ----
  float w0z[4], w0r[4], w0c[4], bzv[4], brv[4], bcv[4], wov[4], bqv[2];
  #pragma unroll
  for (int nt = 0; nt < 4; ++nt) {
    int col = nt * 16 + u;
    w0z[nt] = Wz[col]; w0r[nt] = Wr[col]; w0c[nt] = Wc[col];
    bzv[nt] = bz[col]; brv[nt] = br[col]; bcv[nt] = bc[col];
    wov[nt] = Wo[col];
  }
  bqv[0] = bq[u]; bqv[1] = bq[16 + u];
  const float bov = bo[0];

  // ---- persistent per-row state ----
  short8 qh[12];
  {
    short8 qi;
    #pragma unroll
    for (int j = 0; j < 8; ++j) qi[j] = (short)f2bf(bq[g * 8 + j]);
    #pragma unroll
    for (int s = 0; s < 12; ++s) qh[s] = qi;
  }
  f32x4 hreg[4];
  #pragma unroll
  for (int nt = 0; nt < 4; ++nt) hreg[nt] = (f32x4){0.f, 0.f, 0.f, 0.f};
  float xreg[4] = {0.f, 0.f, 0.f, 0.f};

  // initial h=0 hi/lo scatter (serves step 0's gate reads)
  #pragma unroll
  for (int nt = 0; nt < 4; ++nt) {
    int so = scat_off(nt * 16 + u, g);
    scat4_hilo(SCR + R_HH + so, SCR + R_HL + so, hreg[nt]);
  }

  __syncthreads();    // staged shared frags visible; the only barrier

  for (int t = 0; t < 24; ++t) {
    // ---- x input (global latency hides under score MFMAs) ----
    if (t <= 12) {
      int tt = t < 12 ? t : 11;
      #pragma unroll
      for (int reg = 0; reg < 4; ++reg) {
        int b = hb * 16 + g * 4 + reg;
        xreg[reg] = src[(b * 12 + tt) * 512 + n];
      }
    }

    // ---- h_prev frag reads issued early (latency under score loop) ----
    short8 hhi0 = *(const short8*)(SCR + R_HH + (lane << 4));
    short8 hhi1 = *(const short8*)(SCR + R_HH + 1024 + (lane << 4));
    short8 hlo0 = *(const short8*)(SCR + R_HL + (lane << 4));
    short8 hlo1 = *(const short8*)(SCR + R_HL + 1024 + (lane << 4));

    // ---- scores: pure-register MFMA, 72 ops ----
    f32x4 sacc[6];
    #pragma unroll
    for (int nt = 0; nt < 6; ++nt) sacc[nt] = (f32x4){0.f, 0.f, 0.f, 0.f};
    __builtin_amdgcn_s_setprio(1);
    #pragma unroll
    for (int s = 0; s < 12; ++s) {
      #pragma unroll
      for (int nt = 0; nt < 6; ++nt)
        sacc[nt] = MFMA16(qh[s], marr[s * 6 + nt], sacc[nt]);
    }
    __builtin_amdgcn_s_setprio(0);

    // ---- softmax-lite: e = exp(score); row-sums; reciprocals ----
    #pragma unroll
    for (int nt = 0; nt < 6; ++nt)
      #pragma unroll
      for (int reg = 0; reg < 4; ++reg)
        sacc[nt][reg] = __expf(sacc[nt][reg]);
    float invl[4], invg[4];
    #pragma unroll
    for (int reg = 0; reg < 4; ++reg) {
      float sl = (sacc[0][reg] + sacc[1][reg]) + (sacc[2][reg] + sacc[3][reg]);
      sl += __shfl_xor(sl, 1); sl += __shfl_xor(sl, 2);
      sl += __shfl_xor(sl, 4); sl += __shfl_xor(sl, 8);
      invl[reg] = rcpf(sl);
      float sg = sacc[4][reg] + sacc[5][reg];
      sg += __shfl_xor(sg, 1); sg += __shfl_xor(sg, 2);
      sg += __shfl_xor(sg, 4); sg += __shfl_xor(sg, 8);
      invg[reg] = rcpf(sg);
    }

    // ---- unnormalized e scatter -> AL / AG (sacc dies here) ----
    #pragma unroll
    for (int nt = 0; nt < 4; ++nt)
      scat4(SCR + R_AL + scat_off(nt * 16 + u, g), sacc[nt]);
    #pragma unroll
    for (int nt = 0; nt < 2; ++nt)
      scat4(SCR + R_AG + scat_off(nt * 16 + u, g), sacc[4 + nt]);

    // ---- z, r gates: hi/lo split MFMA (W hi+lo from LDS) ----
    f32x4 zacc[4], racc[4];
    #pragma unroll
    for (int nt = 0; nt < 4; ++nt) {
      zacc[nt] = (f32x4){0.f, 0.f, 0.f, 0.f};
      racc[nt] = (f32x4){0.f, 0.f, 0.f, 0.f};
    }
    #pragma unroll
    for (int kc = 0; kc < 2; ++kc) {
      short8 hh = kc ? hhi1 : hhi0;
      short8 hl = kc ? hlo1 : hlo0;
      #pragma unroll
      for (int nt = 0; nt < 4; ++nt) {
        short8 wzh = *(const short8*)(smem + L_W + ((((0 + nt) * 2 + kc) * 2 + 0) << 10) + (lane << 4));
        short8 wzl = *(const short8*)(smem + L_W + ((((0 + nt) * 2 + kc) * 2 + 1) << 10) + (lane << 4));
        zacc[nt] = MFMA16(hh, wzh, zacc[nt]);
        zacc[nt] = MFMA16(hl, wzh, zacc[nt]);
        zacc[nt] = MFMA16(hh, wzl, zacc[nt]);
        short8 wrh = *(const short8*)(smem + L_W + ((((4 + nt) * 2 + kc) * 2 + 0) << 10) + (lane << 4));
        short8 wrl = *(const short8*)(smem + L_W + ((((4 + nt) * 2 + kc) * 2 + 1) << 10) + (lane << 4));
        racc[nt] = MFMA16(hh, wrh, racc[nt]);
        racc[nt] = MFMA16(hl, wrh, racc[nt]);
        racc[nt] = MFMA16(hh, wrl, racc[nt]);
      }
    }

    // ---- sigmoid gates ----
    #pragma unroll
    for (int nt = 0; nt < 4; ++nt)
      #pragma unroll
      for (int reg = 0; reg < 4; ++reg) {
        float zv = zacc[nt][reg] + xreg[reg] * w0z[nt] + bzv[nt];
        zacc[nt][reg] = rcpf(1.0f + __expf(-zv));
        float rv = racc[nt][reg] + xreg[reg] * w0r[nt] + brv[nt];
        racc[nt][reg] = rcpf(1.0f + __expf(-rv));
      }

    // ---- rh = r*h -> RH/RL hi/lo scatter ----
    #pragma unroll
    for (int nt = 0; nt < 4; ++nt) {
      int so = scat_off(nt * 16 + u, g);
      f32x4 rh;
      #pragma unroll
      for (int reg = 0; reg < 4; ++reg) rh[reg] = racc[nt][reg] * hreg[nt][reg];
      scat4_hilo(SCR + R_RH + so, SCR + R_RL + so, rh);
    }

    // ---- attention context: lc = e_l @ lmean, gc = e_g @ gmean ----
    short8 alf0 = *(const short8*)(SCR + R_AL + (lane << 4));
    short8 alf1 = *(const short8*)(SCR + R_AL + 1024 + (lane << 4));
    short8 agf  = *(const short8*)(SCR + R_AG + (lane << 4));
    f32x4 lacc[2], gacc[2];
    #pragma unroll
    for (int nt = 0; nt < 2; ++nt) {
      lacc[nt] = (f32x4){0.f, 0.f, 0.f, 0.f};
      gacc[nt] = (f32x4){0.f, 0.f, 0.f, 0.f};
      short8 lm0 = *(const short8*)(smem + L_LM + ((0 * 2 + nt) << 10) + (lane << 4));
      short8 lm1 = *(const short8*)(smem + L_LM + ((1 * 2 + nt) << 10) + (lane << 4));
      short8 gm  = *(const short8*)(smem + L_LM + 4096 + (nt << 10) + (lane << 4));
      lacc[nt] = MFMA16(alf0, lm0, lacc[nt]);
      lacc[nt] = MFMA16(alf1, lm1, lacc[nt]);
      gacc[nt] = MFMA16(agf, gm, gacc[nt]);
    }

    // ---- rh reads + Wc MFMA -> hacc ----
    short8 rhh0 = *(const short8*)(SCR + R_RH + (lane << 4));
    short8 rhh1 = *(const short8*)(SCR + R_RH + 1024 + (lane << 4));
    short8 rhl0 = *(const short8*)(SCR + R_RL + (lane << 4));
    short8 rhl1 = *(const short8*)(SCR + R_RL + 1024 + (lane << 4));
    f32x4 hacc[4];
    #pragma unroll
    for (int nt = 0; nt < 4; ++nt) hacc[nt] = (f32x4){0.f, 0.f, 0.f, 0.f};
    #pragma unroll
    for (int kc = 0; kc < 2; ++kc) {
      short8 hh = kc ? rhh1 : rhh0;
      short8 hl = kc ? rhl1 : rhl0;
      #pragma unroll
      for (int nt = 0; nt < 4; ++nt) {
        short8 wch = *(const short8*)(smem + L_W + ((((8 + nt) * 2 + kc) * 2 + 0) << 10) + (lane << 4));
        short8 wcl = *(const short8*)(smem + L_W + ((((8 + nt) * 2 + kc) * 2 + 1) << 10) + (lane << 4));
        hacc[nt] = MFMA16(hh, wch, hacc[nt]);
        hacc[nt] = MFMA16(hl, wch, hacc[nt]);
        hacc[nt] = MFMA16(hh, wcl, hacc[nt]);
      }
    }

    // ---- fused = [lc*invl | gc*invg] scatter -> FU ----
    #pragma unroll
    for (int nt = 0; nt < 2; ++nt) {
      f32x4 lv, gv;
      #pragma unroll
      for (int reg = 0; reg < 4; ++reg) {
        lv[reg] = lacc[nt][reg] * invl[reg];
        gv[reg] = gacc[nt][reg] * invg[reg];
      }
      scat4(SCR + R_FU + scat_off(nt * 16 + u, g), lv);
      scat4(SCR + R_FU + scat_off(32 + nt * 16 + u, g), gv);
    }
    short8 fuf0 = *(const short8*)(SCR + R_FU + (lane << 4));
    short8 fuf1 = *(const short8*)(SCR + R_FU + 1024 + (lane << 4));

    // ---- ctx = fused @ nsw[n] (nsw frags from per-wave LDS) ----
    f32x4 cacc[4];
    #pragma unroll
    for (int nt = 0; nt < 4; ++nt) {
      short8 nf0 = *(const short8*)(SCR + R_NSW + ((0 * 4 + nt) << 10) + (lane << 4));
      short8 nf1 = *(const short8*)(SCR + R_NSW + ((1 * 4 + nt) << 10) + (lane << 4));
      cacc[nt] = (f32x4){0.f, 0.f, 0.f, 0.f};
      cacc[nt] = MFMA16(fuf0, nf0, cacc[nt]);
      cacc[nt] = MFMA16(fuf1, nf1, cacc[nt]);
    }

    // ---- combine: tanh + GRU update ----
    #pragma unroll
    for (int nt = 0; nt < 4; ++nt)
      #pragma unroll
      for (int reg = 0; reg < 4; ++reg) {
        float pv = hacc[nt][reg] + cacc[nt][reg] + xreg[reg] * w0c[nt] + bcv[nt];
        float tdenom = rcpf(1.0f + __expf(2.0f * pv));
        float hc = 1.0f - 2.0f * tdenom;               // tanh(pv)
        float zv = zacc[nt][reg];
        hreg[nt][reg] = (1.0f - zv) * hreg[nt][reg] + zv * hc;
      }

    // ---- h_new hi/lo scatter -> HH/HL (serves q-path now AND next step) ----
    #pragma unroll
    for (int nt = 0; nt < 4; ++nt) {
      int so = scat_off(nt * 16 + u, g);
      scat4_hilo(SCR + R_HH + so, SCR + R_HL + so, hreg[nt]);
    }
    short8 nh0 = *(const short8*)(SCR + R_HH + (lane << 4));
    short8 nh1 = *(const short8*)(SCR + R_HH + 1024 + (lane << 4));

    // ---- qnew = h_new @ Wq + bq (Wq frags from LDS) ----
    f32x4 qacc[2];
    #pragma unroll
    for (int nt = 0; nt < 2; ++nt) {
      short8 wq0 = *(const short8*)(smem + L_WQ + ((nt * 2 + 0) << 10) + (lane << 4));
      short8 wq1 = *(const short8*)(smem + L_WQ + ((nt * 2 + 1) << 10) + (lane << 4));
      qacc[nt] = (f32x4){0.f, 0.f, 0.f, 0.f};
      qacc[nt] = MFMA16(nh0, wq0, qacc[nt]);
      qacc[nt] = MFMA16(nh1, wq1, qacc[nt]);
      #pragma unroll
      for (int reg = 0; reg < 4; ++reg) qacc[nt][reg] += bqv[nt];
    }
    #pragma unroll
    for (int nt = 0; nt < 2; ++nt)
      scat4(SCR + R_QQ + scat_off(nt * 16 + u, g), qacc[nt]);
    short8 qnf = *(const short8*)(SCR + R_QQ + (lane << 4));
    #pragma unroll
    for (int s = 0; s < 11; ++s) qh[s] = qh[s + 1];
    qh[11] = qnf;

    // ---- decoder head ----
    if (t >= 12) {
      #pragma unroll
      for (int reg = 0; reg < 4; ++reg) {
        float yp = hreg[0][reg] * wov[0] + hreg[1][reg] * wov[1] +
                   hreg[2][reg] * wov[2] + hreg[3][reg] * wov[3];
        yp += __shfl_xor(yp, 1); yp += __shfl_xor(yp, 2);
        yp += __shfl_xor(yp, 4); yp += __shfl_xor(yp, 8);
        float yv = yp + bov;
        xreg[reg] = yv;
        if (u == 0) {
          int b = hb * 16 + g * 4 + reg;
          out[(b * 12 + (t - 12)) * 512 + n] = yv;
        }
      }
    }
  }
}

// ===========================================================================
extern "C" void kernel_launch(void* const* d_in, const int* in_sizes, int n_in,
                              void* d_out, int out_size, void* d_ws, size_t ws_size,
                              hipStream_t stream) {
  const float* src  = (const float*)d_in[0];
  const float* lmem = (const float*)d_in[1];
  const float* gmem = (const float*)d_in[2];
  const float* Wq   = (const float*)d_in[3];
  const float* bq   = (const float*)d_in[4];
  const float* emb  = (const float*)d_in[5];
  const float* pool = (const float*)d_in[6];
  const float* Wz   = (const float*)d_in[7];
  const float* bz   = (const float*)d_in[8];
  const float* Wr   = (const float*)d_in[9];
  const float* br   = (const float*)d_in[10];
  const float* Wc   = (const float*)d_in[11];
  const float* bc   = (const float*)d_in[12];
  const float* Wo   = (const float*)d_in[13];
  const float* bo   = (const float*)d_in[14];
  float* out = (float*)d_out;
  unsigned short* ws = (unsigned short*)d_ws;

  dyna_prep<<<260, 256, 0, stream>>>(lmem, gmem, Wq, Wz, Wr, Wc, ws);

  (void)hipFuncSetAttribute((const void*)dyna_main,
                            hipFuncAttributeMaxDynamicSharedMemorySize,
                            SMEM_BYTES);
  dyna_main<<<256, 256, SMEM_BYTES, stream>>>(src, emb, pool, bq, Wz, bz, Wr, br,
                                              Wc, bc, Wo, bo, ws, out);
}